// Round 6
// baseline (1556.332 us; speedup 1.0000x reference)
//
#include <hip/hip_runtime.h>
#include <math.h>

#define NN 100000
#define NE 1600000
#define NG 64
#define F  128

constexpr int SCAN_CHUNK = 1024;                       // 256 threads * 4
constexpr int NB_SCAN = (NN + SCAN_CHUNK - 1) / SCAN_CHUNK;  // 98
constexpr int NPASS = 8;                               // one dst-window per XCD
constexpr int PASS_W = (NN + NPASS - 1) / NPASS;       // 12500 nodes per window
constexpr int REGION_CAP = 49152;                      // per (window,xcd) edge slab (exp 25000)
constexpr int NB_PART = 1024;                          // partition grid (multiple of 8)

typedef __bf16 bf16x8 __attribute__((ext_vector_type(8)));
typedef float  f32x4  __attribute__((ext_vector_type(4)));

__device__ __forceinline__ float b2f(unsigned short u) {
    union { unsigned i; float f; } v; v.i = ((unsigned)u) << 16; return v.f;
}
__device__ __forceinline__ float b2f_lo(unsigned u) {
    union { unsigned i; float f; } v; v.i = u << 16; return v.f;
}
__device__ __forceinline__ float b2f_hi(unsigned u) {
    union { unsigned i; float f; } v; v.i = u & 0xffff0000u; return v.f;
}
__device__ __forceinline__ unsigned short f2b(float f) {
    union { float f; unsigned i; } v; v.f = f;
    unsigned i = v.i;
    return (unsigned short)((i + 0x7fffu + ((i >> 16) & 1u)) >> 16);  // RNE
}

__global__ __launch_bounds__(256) void k_dinv(const int* __restrict__ cnt, float* __restrict__ dinv) {
    int i = blockIdx.x * 256 + threadIdx.x;
    if (i < NN) dinv[i] = rsqrtf((float)cnt[i] + 1.0f);
}

// ---------------- phase A: degree count + partition edges into (window,xcd) slabs --------
// Dense wave-aggregated appends: for each of the 8 dst-windows, the wave claims a
// contiguous range in slab [w][xcd] with ONE atomic, lanes write rank-ordered -> writes
// are sequential (no partial-line RMW amplification). xcd = blockIdx&7 (round-robin map).
__global__ __launch_bounds__(256) void k_part(const int* __restrict__ src, const int* __restrict__ dst,
                                              int* __restrict__ cnt, int* __restrict__ tails,
                                              int2* __restrict__ part) {
    int xcd = blockIdx.x & 7;
    int lane = threadIdx.x & 63;
    for (int e = blockIdx.x * 256 + threadIdx.x; e < NE; e += NB_PART * 256) {
        int d = dst[e];
        int s = src[e];
        atomicAdd(&cnt[d], 1);
        int w = d / PASS_W;
#pragma unroll
        for (int wi = 0; wi < NPASS; ++wi) {
            unsigned long long m = __ballot(w == wi);
            if (m == 0) continue;                       // wave-uniform
            int leader = __ffsll((unsigned long long)m) - 1;
            int nset = __popcll(m);
            int base = 0;
            if (lane == leader) base = atomicAdd(&tails[wi * 8 + xcd], nset);
            base = __shfl(base, leader);
            if (w == wi) {
                int rank = __popcll(m & ((1ull << lane) - 1ull));
                part[(size_t)(wi * 8 + xcd) * REGION_CAP + base + rank] = make_int2(s, d);
            }
        }
    }
}

// ---------------- prefix scan (3 kernels) ----------------
__global__ __launch_bounds__(256) void k_scan1(const int* __restrict__ cnt, int* __restrict__ bsum) {
    __shared__ int sh[256];
    int b = blockIdx.x, t = threadIdx.x;
    int base = b * SCAN_CHUNK + t * 4;
    int s = 0;
#pragma unroll
    for (int u = 0; u < 4; ++u) { int i = base + u; if (i < NN) s += cnt[i]; }
    sh[t] = s; __syncthreads();
    for (int d = 128; d > 0; d >>= 1) { if (t < d) sh[t] += sh[t + d]; __syncthreads(); }
    if (t == 0) bsum[b] = sh[0];
}

__global__ __launch_bounds__(128) void k_scan2(const int* __restrict__ bsum, int* __restrict__ boff) {
    __shared__ int sh[128];
    int t = threadIdx.x;
    int v = (t < NB_SCAN) ? bsum[t] : 0;
    sh[t] = v; __syncthreads();
    for (int d = 1; d < 128; d <<= 1) {
        int x = (t >= d) ? sh[t - d] : 0;
        __syncthreads();
        sh[t] += x;
        __syncthreads();
    }
    if (t < NB_SCAN) boff[t] = sh[t] - v;  // exclusive
}

__global__ __launch_bounds__(256) void k_scan3(const int* __restrict__ cnt, const int* __restrict__ boff,
                                               int* __restrict__ row_start, int* __restrict__ cursor) {
    __shared__ int sh[256];
    int b = blockIdx.x, t = threadIdx.x;
    int base = b * SCAN_CHUNK + t * 4;
    int v[4]; int sum = 0;
#pragma unroll
    for (int u = 0; u < 4; ++u) { int i = base + u; v[u] = (i < NN) ? cnt[i] : 0; sum += v[u]; }
    sh[t] = sum; __syncthreads();
    for (int d = 1; d < 256; d <<= 1) {
        int x = (t >= d) ? sh[t - d] : 0;
        __syncthreads();
        sh[t] += x;
        __syncthreads();
    }
    int run = boff[b] + (sh[t] - sum);
#pragma unroll
    for (int u = 0; u < 4; ++u) {
        int i = base + u;
        if (i < NN) { row_start[i] = run; cursor[i] = run; run += v[u]; }
    }
    if (b == 0 && t == 0) row_start[NN] = NE;
}

// ---------------- phase B: windowed scatter (L2-resident per XCD) ----------------
// pass = bid&7 -> XCD; reads only window w's slabs (~1.6MB) and writes its col
// window (~0.8MB) + cursor slice (50KB): everything fits one XCD's 4MB L2.
__global__ __launch_bounds__(256) void k_scatter2(const int* __restrict__ tails,
                                                  const int2* __restrict__ part,
                                                  int* __restrict__ cursor, int* __restrict__ col) {
    int w = blockIdx.x & 7;
    int slice = blockIdx.x >> 3;
    int nslice = gridDim.x >> 3;
    for (int x = 0; x < 8; ++x) {
        int n = tails[w * 8 + x];
        if (n > REGION_CAP) n = REGION_CAP;
        const int2* p = part + (size_t)(w * 8 + x) * REGION_CAP;
        for (int i = slice * 256 + threadIdx.x; i < n; i += nslice * 256) {
            int2 sd = p[i];
            int pos = atomicAdd(&cursor[sd.y], 1);
            col[pos] = sd.x;
        }
    }
}

// ---------------- W prep: Wt_bf16[n][k] = bf16(W[k][n]) ----------------
__global__ __launch_bounds__(256) void k_wprep(const float* __restrict__ W, unsigned short* __restrict__ Wt) {
    int idx = blockIdx.x * 256 + threadIdx.x;   // 16384
    int k = idx >> 7, n = idx & 127;
    Wt[n * F + k] = f2b(W[idx]);
}

// ---------------- MFMA GEMM: C[r,:] = dinv[r] * (A[r,:] @ W), bf16 out, fp32 acc ----------
template <bool FP32IN>
__global__ __launch_bounds__(256) void k_gemm_mfma(const void* __restrict__ Av,
                                                   const unsigned short* __restrict__ Wt,
                                                   const float* __restrict__ dinv,
                                                   unsigned short* __restrict__ C) {
    __shared__ unsigned short Ws[F * F];  // 32 KB, swizzled: byte ^= (n&7)<<4
    int tid = threadIdx.x;
    int wid = tid >> 6;
    int lane = tid & 63;
    int l15 = lane & 15, l4 = lane >> 4;
    int row0 = blockIdx.x * 128 + wid * 32;

    bf16x8 af[2][4];
#pragma unroll
    for (int mf = 0; mf < 2; ++mf) {
        int r = row0 + mf * 16 + l15;
        if (r > NN - 1) r = NN - 1;
        if (FP32IN) {
            const float* rp = (const float*)Av + (size_t)r * F;
#pragma unroll
            for (int ks = 0; ks < 4; ++ks) {
                float4 v0 = *(const float4*)(rp + ks * 32 + l4 * 8);
                float4 v1 = *(const float4*)(rp + ks * 32 + l4 * 8 + 4);
                bf16x8 a;
                a[0] = (__bf16)v0.x; a[1] = (__bf16)v0.y; a[2] = (__bf16)v0.z; a[3] = (__bf16)v0.w;
                a[4] = (__bf16)v1.x; a[5] = (__bf16)v1.y; a[6] = (__bf16)v1.z; a[7] = (__bf16)v1.w;
                af[mf][ks] = a;
            }
        } else {
            const unsigned short* rp = (const unsigned short*)Av + (size_t)r * F;
#pragma unroll
            for (int ks = 0; ks < 4; ++ks)
                af[mf][ks] = *(const bf16x8*)(rp + ks * 32 + l4 * 8);
        }
    }

#pragma unroll
    for (int p = 0; p < 8; ++p) {
        int idx16 = p * 256 + tid;          // 16-byte unit index, 2048 total
        int n = idx16 >> 4;
        float4 v = *(const float4*)((const char*)Wt + (size_t)idx16 * 16);
        *(float4*)((char*)Ws + (((unsigned)idx16 * 16) ^ (unsigned)((n & 7) << 4))) = v;
    }
    __syncthreads();

    f32x4 acc[2][8];
#pragma unroll
    for (int mf = 0; mf < 2; ++mf)
#pragma unroll
        for (int nf = 0; nf < 8; ++nf) acc[mf][nf] = (f32x4){0.f, 0.f, 0.f, 0.f};

#pragma unroll
    for (int ks = 0; ks < 4; ++ks) {
        bf16x8 bfr[8];
#pragma unroll
        for (int nf = 0; nf < 8; ++nf) {
            int n = nf * 16 + l15;
            unsigned byte = (unsigned)(n * 256 + ks * 64 + l4 * 16) ^ (unsigned)((n & 7) << 4);
            bfr[nf] = *(const bf16x8*)((const char*)Ws + byte);
        }
#pragma unroll
        for (int nf = 0; nf < 8; ++nf) {
            acc[0][nf] = __builtin_amdgcn_mfma_f32_16x16x32_bf16(af[0][ks], bfr[nf], acc[0][nf], 0, 0, 0);
            acc[1][nf] = __builtin_amdgcn_mfma_f32_16x16x32_bf16(af[1][ks], bfr[nf], acc[1][nf], 0, 0, 0);
        }
    }

#pragma unroll
    for (int mf = 0; mf < 2; ++mf)
#pragma unroll
        for (int reg = 0; reg < 4; ++reg) {
            int r = row0 + mf * 16 + l4 * 4 + reg;
            if (r < NN) {
                float di = dinv[r];
#pragma unroll
                for (int nf = 0; nf < 8; ++nf)
                    C[(size_t)r * F + nf * 16 + l15] = f2b(di * acc[mf][nf][reg]);
            }
        }
}

// ---------------- SpMM aggregation + bias + optional ELU (bf16 io, fp32 acc) ----------------
// xw rows pre-scaled by dinv. out[i] = dinv[i]*(sum_j xw'[j] + xw'[i]) + b.
// block = 1 node, 64 threads; thread t handles cols 2t,2t+1 (1 dword per lane).
// Edge loop 8-deep (8 independent gathers in flight per wave; MLP fix).
__global__ __launch_bounds__(64) void k_spmm(const unsigned short* __restrict__ xw,
                                             const int* __restrict__ row_start,
                                             const int* __restrict__ col,
                                             const float* __restrict__ dinv,
                                             const float* __restrict__ bias,
                                             unsigned short* __restrict__ hout,
                                             int do_elu) {
    int i = blockIdx.x;
    int t = threadIdx.x;
    int s = row_start[i], e = row_start[i + 1];
    const unsigned* base = (const unsigned*)xw;   // row j starts at dword j*64
    float a0 = 0.f, a1 = 0.f;
    for (int p = s; p < e; p += 8) {
        int j[8];
        unsigned u[8];
#pragma unroll
        for (int q = 0; q < 8; ++q) {
            int pq = (p + q < e) ? p + q : p;
            j[q] = col[pq];
        }
#pragma unroll
        for (int q = 0; q < 8; ++q) u[q] = base[(size_t)j[q] * 64 + t];
        a0 += b2f_lo(u[0]);
        a1 += b2f_hi(u[0]);
#pragma unroll
        for (int q = 1; q < 8; ++q) {
            float mq = (p + q < e) ? 1.f : 0.f;
            a0 += mq * b2f_lo(u[q]);
            a1 += mq * b2f_hi(u[q]);
        }
    }
    float di = dinv[i];
    unsigned us = base[(size_t)i * 64 + t];
    float v0 = di * (a0 + b2f_lo(us)) + bias[t * 2];
    float v1 = di * (a1 + b2f_hi(us)) + bias[t * 2 + 1];
    if (do_elu) {
        v0 = (v0 > 0.f) ? v0 : (__expf(v0) - 1.f);
        v1 = (v1 > 0.f) ? v1 : (__expf(v1) - 1.f);
    }
    unsigned w = (unsigned)f2b(v0) | ((unsigned)f2b(v1) << 16);
    *(unsigned*)&hout[(size_t)i * F + t * 2] = w;
}

// ---------------- graph boundaries by binary search ----------------
__global__ __launch_bounds__(128) void k_gstart(const int* __restrict__ batch, int* __restrict__ gstart) {
    int g = threadIdx.x;
    if (g > NG) return;
    if (g == NG) { gstart[NG] = NN; return; }
    int lo = 0, hi = NN;
    while (lo < hi) { int mid = (lo + hi) >> 1; if (batch[mid] < g) lo = mid + 1; else hi = mid; }
    gstart[g] = lo;
}

// ---------------- mean pool (partial sums, atomic combine) ----------------
__global__ __launch_bounds__(128) void k_pool(const unsigned short* __restrict__ h,
                                              const int* __restrict__ gstart,
                                              float* __restrict__ poolsum) {
    int g = blockIdx.x >> 4, q = blockIdx.x & 15;
    int c = threadIdx.x;
    int s = gstart[g], e = gstart[g + 1];
    int n = e - s;
    int per = (n + 15) >> 4;
    int ss = s + q * per;
    int ee = min(ss + per, e);
    float acc = 0.f;
    for (int i = ss; i < ee; ++i) acc += b2f(h[(size_t)i * F + c]);
    atomicAdd(&poolsum[g * F + c], acc);
}

// ---------------- final MLP ----------------
__global__ __launch_bounds__(64) void k_mlp(const float* __restrict__ poolsum, const int* __restrict__ gstart,
                                            const float* __restrict__ stats,
                                            const float* __restrict__ fw1, const float* __restrict__ fb1,
                                            const float* __restrict__ fw2, const float* __restrict__ fb2,
                                            const float* __restrict__ fw3, const float* __restrict__ fb3,
                                            float* __restrict__ out) {
    __shared__ float gv[F + 8];
    __shared__ float h1[32];
    __shared__ float h2[16];
    int g = blockIdx.x, t = threadIdx.x;
    float cntf = fmaxf((float)(gstart[g + 1] - gstart[g]), 1.0f);
    for (int c = t; c < F; c += 64) gv[c] = poolsum[g * F + c] / cntf;
    if (t < 8) gv[F + t] = stats[g * 8 + t];
    __syncthreads();
    if (t < 32) {
        float a = fb1[t];
        for (int k = 0; k < F + 8; ++k) a += gv[k] * fw1[k * 32 + t];
        h1[t] = fmaxf(a, 0.f);
    }
    __syncthreads();
    if (t < 16) {
        float a = fb2[t];
        for (int k = 0; k < 32; ++k) a += h1[k] * fw2[k * 16 + t];
        h2[t] = fmaxf(a, 0.f);
    }
    __syncthreads();
    if (t == 0) {
        float a = fb3[0];
        for (int k = 0; k < 16; ++k) a += h2[k] * fw3[k];
        out[g] = a;
    }
}

extern "C" void kernel_launch(void* const* d_in, const int* in_sizes, int n_in,
                              void* d_out, int out_size, void* d_ws, size_t ws_size,
                              hipStream_t stream) {
    const float* x     = (const float*)d_in[0];
    const int*   ei    = (const int*)d_in[1];
    const int*   batch = (const int*)d_in[2];
    const float* stats = (const float*)d_in[3];
    const float* W1 = (const float*)d_in[4];
    const float* b1 = (const float*)d_in[5];
    const float* W2 = (const float*)d_in[6];
    const float* b2 = (const float*)d_in[7];
    const float* W3 = (const float*)d_in[8];
    const float* b3 = (const float*)d_in[9];
    const float* fw1 = (const float*)d_in[10];
    const float* fb1 = (const float*)d_in[11];
    const float* fw2 = (const float*)d_in[12];
    const float* fb2 = (const float*)d_in[13];
    const float* fw3 = (const float*)d_in[14];
    const float* fb3 = (const float*)d_in[15];
    float* out = (float*)d_out;

    const int* srcp = ei;
    const int* dstp = ei + NE;

    char* w = (char*)d_ws;
    size_t off = 0;
    auto take = [&](size_t bytes) -> char* {
        char* p = w + off;
        off += (bytes + 255) & ~size_t(255);
        return p;
    };
    int*   cnt       = (int*)take((size_t)NN * 4);
    int*   row_start = (int*)take((size_t)(NN + 1) * 4);
    int*   cursor    = (int*)take((size_t)NN * 4);
    int*   col       = (int*)take((size_t)NE * 4);
    float* dinv      = (float*)take((size_t)NN * 4);
    int*   bsum      = (int*)take((size_t)NB_SCAN * 4);
    int*   boff      = (int*)take((size_t)NB_SCAN * 4);
    int*   gstart    = (int*)take((size_t)(NG + 1) * 4);
    float* poolsum   = (float*)take((size_t)NG * F * 4);
    int*   tails     = (int*)take((size_t)64 * 4);
    int2*  part      = (int2*)take((size_t)64 * REGION_CAP * 8);
    unsigned short* Wt   = (unsigned short*)take((size_t)F * F * 2);
    unsigned short* bufA = (unsigned short*)take((size_t)NN * F * 2);
    unsigned short* bufB = (unsigned short*)take((size_t)NN * F * 2);

    hipMemsetAsync(cnt, 0, (size_t)NN * 4, stream);
    hipMemsetAsync(tails, 0, (size_t)64 * 4, stream);
    hipMemsetAsync(poolsum, 0, (size_t)NG * F * 4, stream);

    k_part<<<NB_PART, 256, 0, stream>>>(srcp, dstp, cnt, tails, part);
    k_dinv<<<(NN + 255) / 256, 256, 0, stream>>>(cnt, dinv);
    k_scan1<<<NB_SCAN, 256, 0, stream>>>(cnt, bsum);
    k_scan2<<<1, 128, 0, stream>>>(bsum, boff);
    k_scan3<<<NB_SCAN, 256, 0, stream>>>(cnt, boff, row_start, cursor);
    k_scatter2<<<8 * 128, 256, 0, stream>>>(tails, part, cursor, col);
    k_gstart<<<1, 128, 0, stream>>>(batch, gstart);

    const int gemm_grid = (NN + 127) / 128;

    // layer 1 (fp32 input)
    k_wprep<<<64, 256, 0, stream>>>(W1, Wt);
    k_gemm_mfma<true><<<gemm_grid, 256, 0, stream>>>(x, Wt, dinv, bufA);
    k_spmm<<<NN, 64, 0, stream>>>(bufA, row_start, col, dinv, b1, bufB, 1);
    // layer 2
    k_wprep<<<64, 256, 0, stream>>>(W2, Wt);
    k_gemm_mfma<false><<<gemm_grid, 256, 0, stream>>>(bufB, Wt, dinv, bufA);
    k_spmm<<<NN, 64, 0, stream>>>(bufA, row_start, col, dinv, b2, bufB, 1);
    // layer 3
    k_wprep<<<64, 256, 0, stream>>>(W3, Wt);
    k_gemm_mfma<false><<<gemm_grid, 256, 0, stream>>>(bufB, Wt, dinv, bufA);
    k_spmm<<<NN, 64, 0, stream>>>(bufA, row_start, col, dinv, b3, bufB, 0);

    k_pool<<<NG * 16, F, 0, stream>>>(bufB, gstart, poolsum);
    k_mlp<<<NG, 64, 0, stream>>>(poolsum, gstart, stats, fw1, fb1, fw2, fb2, fw3, fb3, out);
}

// Round 7
// 438.136 us; speedup vs baseline: 3.5522x; 3.5522x over previous
//
#include <hip/hip_runtime.h>
#include <math.h>

#define NN 100000
#define NE 1600000
#define NG 64
#define F  128

constexpr int SCAN_CHUNK = 1024;                       // 256 threads * 4
constexpr int NB_SCAN = (NN + SCAN_CHUNK - 1) / SCAN_CHUNK;  // 98
constexpr int NPASS = 8;                               // one dst-window per XCD
constexpr int PASS_W = (NN + NPASS - 1) / NPASS;       // 12500 nodes per window

typedef __bf16 bf16x8 __attribute__((ext_vector_type(8)));
typedef float  f32x4  __attribute__((ext_vector_type(4)));

__device__ __forceinline__ float b2f(unsigned short u) {
    union { unsigned i; float f; } v; v.i = ((unsigned)u) << 16; return v.f;
}
__device__ __forceinline__ float b2f_lo(unsigned u) {
    union { unsigned i; float f; } v; v.i = u << 16; return v.f;
}
__device__ __forceinline__ float b2f_hi(unsigned u) {
    union { unsigned i; float f; } v; v.i = u & 0xffff0000u; return v.f;
}
__device__ __forceinline__ unsigned short f2b(float f) {
    union { float f; unsigned i; } v; v.f = f;
    unsigned i = v.i;
    return (unsigned short)((i + 0x7fffu + ((i >> 16) & 1u)) >> 16);  // RNE
}

// ---------------- degree count ----------------
__global__ __launch_bounds__(256) void k_count(const int* __restrict__ dst, int* __restrict__ cnt) {
    int e = blockIdx.x * 256 + threadIdx.x;
    if (e < NE) atomicAdd(&cnt[__builtin_nontemporal_load(&dst[e])], 1);
}

__global__ __launch_bounds__(256) void k_dinv(const int* __restrict__ cnt, float* __restrict__ dinv) {
    int i = blockIdx.x * 256 + threadIdx.x;
    if (i < NN) dinv[i] = rsqrtf((float)cnt[i] + 1.0f);
}

// ---------------- prefix scan (3 kernels) ----------------
__global__ __launch_bounds__(256) void k_scan1(const int* __restrict__ cnt, int* __restrict__ bsum) {
    __shared__ int sh[256];
    int b = blockIdx.x, t = threadIdx.x;
    int base = b * SCAN_CHUNK + t * 4;
    int s = 0;
#pragma unroll
    for (int u = 0; u < 4; ++u) { int i = base + u; if (i < NN) s += cnt[i]; }
    sh[t] = s; __syncthreads();
    for (int d = 128; d > 0; d >>= 1) { if (t < d) sh[t] += sh[t + d]; __syncthreads(); }
    if (t == 0) bsum[b] = sh[0];
}

__global__ __launch_bounds__(128) void k_scan2(const int* __restrict__ bsum, int* __restrict__ boff) {
    __shared__ int sh[128];
    int t = threadIdx.x;
    int v = (t < NB_SCAN) ? bsum[t] : 0;
    sh[t] = v; __syncthreads();
    for (int d = 1; d < 128; d <<= 1) {
        int x = (t >= d) ? sh[t - d] : 0;
        __syncthreads();
        sh[t] += x;
        __syncthreads();
    }
    if (t < NB_SCAN) boff[t] = sh[t] - v;  // exclusive
}

__global__ __launch_bounds__(256) void k_scan3(const int* __restrict__ cnt, const int* __restrict__ boff,
                                               int* __restrict__ row_start, int* __restrict__ cursor) {
    __shared__ int sh[256];
    int b = blockIdx.x, t = threadIdx.x;
    int base = b * SCAN_CHUNK + t * 4;
    int v[4]; int sum = 0;
#pragma unroll
    for (int u = 0; u < 4; ++u) { int i = base + u; v[u] = (i < NN) ? cnt[i] : 0; sum += v[u]; }
    sh[t] = sum; __syncthreads();
    for (int d = 1; d < 256; d <<= 1) {
        int x = (t >= d) ? sh[t - d] : 0;
        __syncthreads();
        sh[t] += x;
        __syncthreads();
    }
    int run = boff[b] + (sh[t] - sum);
#pragma unroll
    for (int u = 0; u < 4; ++u) {
        int i = base + u;
        if (i < NN) { row_start[i] = run; cursor[i] = run; run += v[u]; }
    }
    if (b == 0 && t == 0) row_start[NN] = NE;
}

// ---------------- scatter, XCD-owned dst windows + non-temporal edge stream ----------------
// pass = bid&7 -> round-robin XCD map: each 12500-node window's col region (~0.8MB) and
// cursor slice (50KB) are owned by ONE XCD's L2. Edge stream read with nt loads so the
// 12.8MB/pass stream does NOT allocate in L2 and can't evict the col window between
// slot-writes (round-5 profile: cacheable stream -> 73MB writeback for 6.4MB col).
__global__ __launch_bounds__(256) void k_scatter(const int* __restrict__ src, const int* __restrict__ dst,
                                                 int* __restrict__ cursor, int* __restrict__ col) {
    int pass = blockIdx.x & (NPASS - 1);
    int e = (blockIdx.x >> 3) * 256 + threadIdx.x;
    if (e < NE) {
        int d = __builtin_nontemporal_load(&dst[e]);
        if ((unsigned)(d - pass * PASS_W) < (unsigned)PASS_W) {
            int s = __builtin_nontemporal_load(&src[e]);
            int p = atomicAdd(&cursor[d], 1);
            col[p] = s;
        }
    }
}

// ---------------- W prep: Wt_bf16[n][k] = bf16(W[k][n]) ----------------
__global__ __launch_bounds__(256) void k_wprep(const float* __restrict__ W, unsigned short* __restrict__ Wt) {
    int idx = blockIdx.x * 256 + threadIdx.x;   // 16384
    int k = idx >> 7, n = idx & 127;
    Wt[n * F + k] = f2b(W[idx]);
}

// ---------------- MFMA GEMM: C[r,:] = dinv[r] * (A[r,:] @ W), bf16 out, fp32 acc ----------
template <bool FP32IN>
__global__ __launch_bounds__(256) void k_gemm_mfma(const void* __restrict__ Av,
                                                   const unsigned short* __restrict__ Wt,
                                                   const float* __restrict__ dinv,
                                                   unsigned short* __restrict__ C) {
    __shared__ unsigned short Ws[F * F];  // 32 KB, swizzled: byte ^= (n&7)<<4
    int tid = threadIdx.x;
    int wid = tid >> 6;
    int lane = tid & 63;
    int l15 = lane & 15, l4 = lane >> 4;
    int row0 = blockIdx.x * 128 + wid * 32;

    bf16x8 af[2][4];
#pragma unroll
    for (int mf = 0; mf < 2; ++mf) {
        int r = row0 + mf * 16 + l15;
        if (r > NN - 1) r = NN - 1;
        if (FP32IN) {
            const float* rp = (const float*)Av + (size_t)r * F;
#pragma unroll
            for (int ks = 0; ks < 4; ++ks) {
                float4 v0 = *(const float4*)(rp + ks * 32 + l4 * 8);
                float4 v1 = *(const float4*)(rp + ks * 32 + l4 * 8 + 4);
                bf16x8 a;
                a[0] = (__bf16)v0.x; a[1] = (__bf16)v0.y; a[2] = (__bf16)v0.z; a[3] = (__bf16)v0.w;
                a[4] = (__bf16)v1.x; a[5] = (__bf16)v1.y; a[6] = (__bf16)v1.z; a[7] = (__bf16)v1.w;
                af[mf][ks] = a;
            }
        } else {
            const unsigned short* rp = (const unsigned short*)Av + (size_t)r * F;
#pragma unroll
            for (int ks = 0; ks < 4; ++ks)
                af[mf][ks] = *(const bf16x8*)(rp + ks * 32 + l4 * 8);
        }
    }

#pragma unroll
    for (int p = 0; p < 8; ++p) {
        int idx16 = p * 256 + tid;          // 16-byte unit index, 2048 total
        int n = idx16 >> 4;
        float4 v = *(const float4*)((const char*)Wt + (size_t)idx16 * 16);
        *(float4*)((char*)Ws + (((unsigned)idx16 * 16) ^ (unsigned)((n & 7) << 4))) = v;
    }
    __syncthreads();

    f32x4 acc[2][8];
#pragma unroll
    for (int mf = 0; mf < 2; ++mf)
#pragma unroll
        for (int nf = 0; nf < 8; ++nf) acc[mf][nf] = (f32x4){0.f, 0.f, 0.f, 0.f};

#pragma unroll
    for (int ks = 0; ks < 4; ++ks) {
        bf16x8 bfr[8];
#pragma unroll
        for (int nf = 0; nf < 8; ++nf) {
            int n = nf * 16 + l15;
            unsigned byte = (unsigned)(n * 256 + ks * 64 + l4 * 16) ^ (unsigned)((n & 7) << 4);
            bfr[nf] = *(const bf16x8*)((const char*)Ws + byte);
        }
#pragma unroll
        for (int nf = 0; nf < 8; ++nf) {
            acc[0][nf] = __builtin_amdgcn_mfma_f32_16x16x32_bf16(af[0][ks], bfr[nf], acc[0][nf], 0, 0, 0);
            acc[1][nf] = __builtin_amdgcn_mfma_f32_16x16x32_bf16(af[1][ks], bfr[nf], acc[1][nf], 0, 0, 0);
        }
    }

#pragma unroll
    for (int mf = 0; mf < 2; ++mf)
#pragma unroll
        for (int reg = 0; reg < 4; ++reg) {
            int r = row0 + mf * 16 + l4 * 4 + reg;
            if (r < NN) {
                float di = dinv[r];
#pragma unroll
                for (int nf = 0; nf < 8; ++nf)
                    C[(size_t)r * F + nf * 16 + l15] = f2b(di * acc[mf][nf][reg]);
            }
        }
}

// ---------------- SpMM aggregation + bias + optional ELU (bf16 io, fp32 acc) ----------------
// xw rows pre-scaled by dinv. out[i] = dinv[i]*(sum_j xw'[j] + xw'[i]) + b.
// block = 1 node, 64 threads; thread t handles cols 2t,2t+1 (1 dword per lane).
// Edge loop 8-deep (8 independent gathers in flight per wave).
__global__ __launch_bounds__(64) void k_spmm(const unsigned short* __restrict__ xw,
                                             const int* __restrict__ row_start,
                                             const int* __restrict__ col,
                                             const float* __restrict__ dinv,
                                             const float* __restrict__ bias,
                                             unsigned short* __restrict__ hout,
                                             int do_elu) {
    int i = blockIdx.x;
    int t = threadIdx.x;
    int s = row_start[i], e = row_start[i + 1];
    const unsigned* base = (const unsigned*)xw;   // row j starts at dword j*64
    float a0 = 0.f, a1 = 0.f;
    for (int p = s; p < e; p += 8) {
        int j[8];
        unsigned u[8];
#pragma unroll
        for (int q = 0; q < 8; ++q) {
            int pq = (p + q < e) ? p + q : p;
            j[q] = col[pq];
        }
#pragma unroll
        for (int q = 0; q < 8; ++q) u[q] = base[(size_t)j[q] * 64 + t];
        a0 += b2f_lo(u[0]);
        a1 += b2f_hi(u[0]);
#pragma unroll
        for (int q = 1; q < 8; ++q) {
            float mq = (p + q < e) ? 1.f : 0.f;
            a0 += mq * b2f_lo(u[q]);
            a1 += mq * b2f_hi(u[q]);
        }
    }
    float di = dinv[i];
    unsigned us = base[(size_t)i * 64 + t];
    float v0 = di * (a0 + b2f_lo(us)) + bias[t * 2];
    float v1 = di * (a1 + b2f_hi(us)) + bias[t * 2 + 1];
    if (do_elu) {
        v0 = (v0 > 0.f) ? v0 : (__expf(v0) - 1.f);
        v1 = (v1 > 0.f) ? v1 : (__expf(v1) - 1.f);
    }
    unsigned w = (unsigned)f2b(v0) | ((unsigned)f2b(v1) << 16);
    *(unsigned*)&hout[(size_t)i * F + t * 2] = w;
}

// ---------------- graph boundaries by binary search ----------------
__global__ __launch_bounds__(128) void k_gstart(const int* __restrict__ batch, int* __restrict__ gstart) {
    int g = threadIdx.x;
    if (g > NG) return;
    if (g == NG) { gstart[NG] = NN; return; }
    int lo = 0, hi = NN;
    while (lo < hi) { int mid = (lo + hi) >> 1; if (batch[mid] < g) lo = mid + 1; else hi = mid; }
    gstart[g] = lo;
}

// ---------------- mean pool (partial sums, atomic combine) ----------------
__global__ __launch_bounds__(128) void k_pool(const unsigned short* __restrict__ h,
                                              const int* __restrict__ gstart,
                                              float* __restrict__ poolsum) {
    int g = blockIdx.x >> 4, q = blockIdx.x & 15;
    int c = threadIdx.x;
    int s = gstart[g], e = gstart[g + 1];
    int n = e - s;
    int per = (n + 15) >> 4;
    int ss = s + q * per;
    int ee = min(ss + per, e);
    float acc = 0.f;
    for (int i = ss; i < ee; ++i) acc += b2f(h[(size_t)i * F + c]);
    atomicAdd(&poolsum[g * F + c], acc);
}

// ---------------- final MLP ----------------
__global__ __launch_bounds__(64) void k_mlp(const float* __restrict__ poolsum, const int* __restrict__ gstart,
                                            const float* __restrict__ stats,
                                            const float* __restrict__ fw1, const float* __restrict__ fb1,
                                            const float* __restrict__ fw2, const float* __restrict__ fb2,
                                            const float* __restrict__ fw3, const float* __restrict__ fb3,
                                            float* __restrict__ out) {
    __shared__ float gv[F + 8];
    __shared__ float h1[32];
    __shared__ float h2[16];
    int g = blockIdx.x, t = threadIdx.x;
    float cntf = fmaxf((float)(gstart[g + 1] - gstart[g]), 1.0f);
    for (int c = t; c < F; c += 64) gv[c] = poolsum[g * F + c] / cntf;
    if (t < 8) gv[F + t] = stats[g * 8 + t];
    __syncthreads();
    if (t < 32) {
        float a = fb1[t];
        for (int k = 0; k < F + 8; ++k) a += gv[k] * fw1[k * 32 + t];
        h1[t] = fmaxf(a, 0.f);
    }
    __syncthreads();
    if (t < 16) {
        float a = fb2[t];
        for (int k = 0; k < 32; ++k) a += h1[k] * fw2[k * 16 + t];
        h2[t] = fmaxf(a, 0.f);
    }
    __syncthreads();
    if (t == 0) {
        float a = fb3[0];
        for (int k = 0; k < 16; ++k) a += h2[k] * fw3[k];
        out[g] = a;
    }
}

extern "C" void kernel_launch(void* const* d_in, const int* in_sizes, int n_in,
                              void* d_out, int out_size, void* d_ws, size_t ws_size,
                              hipStream_t stream) {
    const float* x     = (const float*)d_in[0];
    const int*   ei    = (const int*)d_in[1];
    const int*   batch = (const int*)d_in[2];
    const float* stats = (const float*)d_in[3];
    const float* W1 = (const float*)d_in[4];
    const float* b1 = (const float*)d_in[5];
    const float* W2 = (const float*)d_in[6];
    const float* b2 = (const float*)d_in[7];
    const float* W3 = (const float*)d_in[8];
    const float* b3 = (const float*)d_in[9];
    const float* fw1 = (const float*)d_in[10];
    const float* fb1 = (const float*)d_in[11];
    const float* fw2 = (const float*)d_in[12];
    const float* fb2 = (const float*)d_in[13];
    const float* fw3 = (const float*)d_in[14];
    const float* fb3 = (const float*)d_in[15];
    float* out = (float*)d_out;

    const int* srcp = ei;
    const int* dstp = ei + NE;

    char* w = (char*)d_ws;
    size_t off = 0;
    auto take = [&](size_t bytes) -> char* {
        char* p = w + off;
        off += (bytes + 255) & ~size_t(255);
        return p;
    };
    int*   cnt       = (int*)take((size_t)NN * 4);
    int*   row_start = (int*)take((size_t)(NN + 1) * 4);
    int*   cursor    = (int*)take((size_t)NN * 4);
    int*   col       = (int*)take((size_t)NE * 4);
    float* dinv      = (float*)take((size_t)NN * 4);
    int*   bsum      = (int*)take((size_t)NB_SCAN * 4);
    int*   boff      = (int*)take((size_t)NB_SCAN * 4);
    int*   gstart    = (int*)take((size_t)(NG + 1) * 4);
    float* poolsum   = (float*)take((size_t)NG * F * 4);
    unsigned short* Wt   = (unsigned short*)take((size_t)F * F * 2);
    unsigned short* bufA = (unsigned short*)take((size_t)NN * F * 2);
    unsigned short* bufB = (unsigned short*)take((size_t)NN * F * 2);

    hipMemsetAsync(cnt, 0, (size_t)NN * 4, stream);
    hipMemsetAsync(poolsum, 0, (size_t)NG * F * 4, stream);

    k_count<<<(NE + 255) / 256, 256, 0, stream>>>(dstp, cnt);
    k_dinv<<<(NN + 255) / 256, 256, 0, stream>>>(cnt, dinv);
    k_scan1<<<NB_SCAN, 256, 0, stream>>>(cnt, bsum);
    k_scan2<<<1, 128, 0, stream>>>(bsum, boff);
    k_scan3<<<NB_SCAN, 256, 0, stream>>>(cnt, boff, row_start, cursor);
    const int chunks = (NE + 255) / 256;
    k_scatter<<<NPASS * chunks, 256, 0, stream>>>(srcp, dstp, cursor, col);
    k_gstart<<<1, 128, 0, stream>>>(batch, gstart);

    const int gemm_grid = (NN + 127) / 128;

    // layer 1 (fp32 input)
    k_wprep<<<64, 256, 0, stream>>>(W1, Wt);
    k_gemm_mfma<true><<<gemm_grid, 256, 0, stream>>>(x, Wt, dinv, bufA);
    k_spmm<<<NN, 64, 0, stream>>>(bufA, row_start, col, dinv, b1, bufB, 1);
    // layer 2
    k_wprep<<<64, 256, 0, stream>>>(W2, Wt);
    k_gemm_mfma<false><<<gemm_grid, 256, 0, stream>>>(bufB, Wt, dinv, bufA);
    k_spmm<<<NN, 64, 0, stream>>>(bufA, row_start, col, dinv, b2, bufB, 1);
    // layer 3
    k_wprep<<<64, 256, 0, stream>>>(W3, Wt);
    k_gemm_mfma<false><<<gemm_grid, 256, 0, stream>>>(bufB, Wt, dinv, bufA);
    k_spmm<<<NN, 64, 0, stream>>>(bufA, row_start, col, dinv, b3, bufB, 0);

    k_pool<<<NG * 16, F, 0, stream>>>(bufB, gstart, poolsum);
    k_mlp<<<NG, 64, 0, stream>>>(poolsum, gstart, stats, fw1, fb1, fw2, fb2, fw3, fb3, out);
}

// Round 8
// 404.438 us; speedup vs baseline: 3.8481x; 1.0833x over previous
//
#include <hip/hip_runtime.h>
#include <math.h>

#define NN 100000
#define NE 1600000
#define NG 64
#define F  128

constexpr int NBUCK = (NN + 127) / 128;     // 782 buckets of 128 nodes
constexpr int NBLK  = 64;                   // hist/place blocks
constexpr int EPB   = NE / NBLK;            // 25000 edges per block (exact)
constexpr int BCAP  = 3072;                 // LDS pair cap per bucket (mean 2046, sigma ~45)

typedef __bf16 bf16x8 __attribute__((ext_vector_type(8)));
typedef float  f32x4  __attribute__((ext_vector_type(4)));

__device__ __forceinline__ float b2f(unsigned short u) {
    union { unsigned i; float f; } v; v.i = ((unsigned)u) << 16; return v.f;
}
__device__ __forceinline__ float b2f_lo(unsigned u) {
    union { unsigned i; float f; } v; v.i = u << 16; return v.f;
}
__device__ __forceinline__ float b2f_hi(unsigned u) {
    union { unsigned i; float f; } v; v.i = u & 0xffff0000u; return v.f;
}
__device__ __forceinline__ unsigned short f2b(float f) {
    union { float f; unsigned i; } v; v.f = f;
    unsigned i = v.i;
    return (unsigned short)((i + 0x7fffu + ((i >> 16) & 1u)) >> 16);  // RNE
}

// ---------------- sort pipeline 1: per-block bucket histogram (LDS, dense write) --------
__global__ __launch_bounds__(256) void k_hist(const int* __restrict__ dst, int* __restrict__ histg) {
    __shared__ int h[NBUCK];
    int blk = blockIdx.x, t = threadIdx.x;
    for (int b = t; b < NBUCK; b += 256) h[b] = 0;
    __syncthreads();
    int s0 = blk * EPB, s1 = s0 + EPB;
    for (int e = s0 + t; e < s1; e += 256) {
        int d = __builtin_nontemporal_load(&dst[e]);
        atomicAdd(&h[d >> 7], 1);
    }
    __syncthreads();
    for (int b = t; b < NBUCK; b += 256) histg[blk * NBUCK + b] = h[b];
}

// ---------------- sort pipeline 2: per-bucket scan over blocks (1 wave) ----------------
__global__ __launch_bounds__(64) void k_boff(const int* __restrict__ histg, int* __restrict__ offs,
                                             int* __restrict__ tot) {
    int b = blockIdx.x, t = threadIdx.x;
    int v = histg[t * NBUCK + b];
    int incl = v;
#pragma unroll
    for (int d = 1; d < 64; d <<= 1) {
        int x = __shfl_up(incl, d);
        if (t >= d) incl += x;
    }
    offs[t * NBUCK + b] = incl - v;   // exclusive over blocks
    if (t == 63) tot[b] = incl;
}

// ---------------- sort pipeline 3: exclusive scan of bucket totals ----------------
__global__ __launch_bounds__(1024) void k_scanb(const int* __restrict__ tot, int* __restrict__ base) {
    __shared__ int sh[1024];
    int t = threadIdx.x;
    int v = (t < NBUCK) ? tot[t] : 0;
    sh[t] = v; __syncthreads();
    for (int d = 1; d < 1024; d <<= 1) {
        int x = (t >= d) ? sh[t - d] : 0;
        __syncthreads();
        sh[t] += x;
        __syncthreads();
    }
    if (t < NBUCK) base[t] = sh[t] - v;      // exclusive
    if (t == NBUCK - 1) base[NBUCK] = sh[t]; // = NE
}

// ---------------- sort pipeline 4: place (src,dst) pairs bucket-partitioned ----------------
__global__ __launch_bounds__(256) void k_place(const int* __restrict__ src, const int* __restrict__ dst,
                                               const int* __restrict__ offs, const int* __restrict__ base,
                                               int2* __restrict__ pair) {
    __shared__ int cur[NBUCK];
    int blk = blockIdx.x, t = threadIdx.x;
    for (int b = t; b < NBUCK; b += 256) cur[b] = base[b] + offs[blk * NBUCK + b];
    __syncthreads();
    int s0 = blk * EPB, s1 = s0 + EPB;
    for (int e = s0 + t; e < s1; e += 256) {
        int d = __builtin_nontemporal_load(&dst[e]);
        int s = __builtin_nontemporal_load(&src[e]);
        int pos = atomicAdd(&cur[d >> 7], 1);
        pair[pos] = make_int2(s, d);
    }
}

// ---------------- sort pipeline 5: per-bucket finalize ----------------
// Stages the bucket's pair slab in LDS; emits cnt/dinv/row_start densely and
// scatters col within an L2-resident ~8KB window. Everything written exactly once.
__global__ __launch_bounds__(256) void k_final(const int2* __restrict__ pair, const int* __restrict__ base,
                                               int* __restrict__ cnt, float* __restrict__ dinv,
                                               int* __restrict__ row_start, int* __restrict__ col) {
    __shared__ int2 lp[BCAP];
    __shared__ int c[128];
    __shared__ int loc[128];
    int b = blockIdx.x, t = threadIdx.x;
    int s0 = base[b], s1 = base[b + 1];
    int n = s1 - s0;
    bool lds_ok = (n <= BCAP);
    for (int i = t; i < 128; i += 256) c[i] = 0;
    __syncthreads();
    if (lds_ok) {
        for (int i = t; i < n; i += 256) {
            int2 sd = pair[s0 + i];
            lp[i] = sd;
            atomicAdd(&c[sd.y & 127], 1);
        }
    } else {
        for (int i = t; i < n; i += 256) atomicAdd(&c[pair[s0 + i].y & 127], 1);
    }
    __syncthreads();
    if (t == 0) {
        int run = 0;
        for (int i = 0; i < 128; ++i) { loc[i] = run; run += c[i]; }
    }
    __syncthreads();
    int g0 = b * 128;
    if (t < 128 && g0 + t < NN) {
        int deg = c[t];
        cnt[g0 + t] = deg;
        dinv[g0 + t] = rsqrtf((float)deg + 1.0f);
        row_start[g0 + t] = s0 + loc[t];
    }
    if (b == NBUCK - 1 && t == 0) row_start[NN] = NE;
    // reuse c[] as cursors
    if (t < 128) c[t] = loc[t];
    __syncthreads();
    if (lds_ok) {
        for (int i = t; i < n; i += 256) {
            int2 sd = lp[i];
            int pos = atomicAdd(&c[sd.y & 127], 1);
            col[s0 + pos] = sd.x;
        }
    } else {
        for (int i = t; i < n; i += 256) {
            int2 sd = pair[s0 + i];
            int pos = atomicAdd(&c[sd.y & 127], 1);
            col[s0 + pos] = sd.x;
        }
    }
}

// ---------------- W prep: Wt_bf16[n][k] = bf16(W[k][n]) ----------------
__global__ __launch_bounds__(256) void k_wprep(const float* __restrict__ W, unsigned short* __restrict__ Wt) {
    int idx = blockIdx.x * 256 + threadIdx.x;   // 16384
    int k = idx >> 7, n = idx & 127;
    Wt[n * F + k] = f2b(W[idx]);
}

// ---------------- MFMA GEMM: C[r,:] = dinv[r] * (A[r,:] @ W), bf16 out, fp32 acc ----------
template <bool FP32IN>
__global__ __launch_bounds__(256) void k_gemm_mfma(const void* __restrict__ Av,
                                                   const unsigned short* __restrict__ Wt,
                                                   const float* __restrict__ dinv,
                                                   unsigned short* __restrict__ C) {
    __shared__ unsigned short Ws[F * F];  // 32 KB, swizzled: byte ^= (n&7)<<4
    int tid = threadIdx.x;
    int wid = tid >> 6;
    int lane = tid & 63;
    int l15 = lane & 15, l4 = lane >> 4;
    int row0 = blockIdx.x * 128 + wid * 32;

    bf16x8 af[2][4];
#pragma unroll
    for (int mf = 0; mf < 2; ++mf) {
        int r = row0 + mf * 16 + l15;
        if (r > NN - 1) r = NN - 1;
        if (FP32IN) {
            const float* rp = (const float*)Av + (size_t)r * F;
#pragma unroll
            for (int ks = 0; ks < 4; ++ks) {
                float4 v0 = *(const float4*)(rp + ks * 32 + l4 * 8);
                float4 v1 = *(const float4*)(rp + ks * 32 + l4 * 8 + 4);
                bf16x8 a;
                a[0] = (__bf16)v0.x; a[1] = (__bf16)v0.y; a[2] = (__bf16)v0.z; a[3] = (__bf16)v0.w;
                a[4] = (__bf16)v1.x; a[5] = (__bf16)v1.y; a[6] = (__bf16)v1.z; a[7] = (__bf16)v1.w;
                af[mf][ks] = a;
            }
        } else {
            const unsigned short* rp = (const unsigned short*)Av + (size_t)r * F;
#pragma unroll
            for (int ks = 0; ks < 4; ++ks)
                af[mf][ks] = *(const bf16x8*)(rp + ks * 32 + l4 * 8);
        }
    }

#pragma unroll
    for (int p = 0; p < 8; ++p) {
        int idx16 = p * 256 + tid;          // 16-byte unit index, 2048 total
        int n = idx16 >> 4;
        float4 v = *(const float4*)((const char*)Wt + (size_t)idx16 * 16);
        *(float4*)((char*)Ws + (((unsigned)idx16 * 16) ^ (unsigned)((n & 7) << 4))) = v;
    }
    __syncthreads();

    f32x4 acc[2][8];
#pragma unroll
    for (int mf = 0; mf < 2; ++mf)
#pragma unroll
        for (int nf = 0; nf < 8; ++nf) acc[mf][nf] = (f32x4){0.f, 0.f, 0.f, 0.f};

#pragma unroll
    for (int ks = 0; ks < 4; ++ks) {
        bf16x8 bfr[8];
#pragma unroll
        for (int nf = 0; nf < 8; ++nf) {
            int n = nf * 16 + l15;
            unsigned byte = (unsigned)(n * 256 + ks * 64 + l4 * 16) ^ (unsigned)((n & 7) << 4);
            bfr[nf] = *(const bf16x8*)((const char*)Ws + byte);
        }
#pragma unroll
        for (int nf = 0; nf < 8; ++nf) {
            acc[0][nf] = __builtin_amdgcn_mfma_f32_16x16x32_bf16(af[0][ks], bfr[nf], acc[0][nf], 0, 0, 0);
            acc[1][nf] = __builtin_amdgcn_mfma_f32_16x16x32_bf16(af[1][ks], bfr[nf], acc[1][nf], 0, 0, 0);
        }
    }

#pragma unroll
    for (int mf = 0; mf < 2; ++mf)
#pragma unroll
        for (int reg = 0; reg < 4; ++reg) {
            int r = row0 + mf * 16 + l4 * 4 + reg;
            if (r < NN) {
                float di = dinv[r];
#pragma unroll
                for (int nf = 0; nf < 8; ++nf)
                    C[(size_t)r * F + nf * 16 + l15] = f2b(di * acc[mf][nf][reg]);
            }
        }
}

// ---------------- SpMM aggregation + bias + optional ELU (bf16 io, fp32 acc) ----------------
// xw rows pre-scaled by dinv. out[i] = dinv[i]*(sum_j xw'[j] + xw'[i]) + b.
// block = 1 node, 64 threads; thread t handles cols 2t,2t+1 (1 dword per lane).
// Edge loop 8-deep (8 independent gathers in flight per wave).
__global__ __launch_bounds__(64) void k_spmm(const unsigned short* __restrict__ xw,
                                             const int* __restrict__ row_start,
                                             const int* __restrict__ col,
                                             const float* __restrict__ dinv,
                                             const float* __restrict__ bias,
                                             unsigned short* __restrict__ hout,
                                             int do_elu) {
    int i = blockIdx.x;
    int t = threadIdx.x;
    int s = row_start[i], e = row_start[i + 1];
    const unsigned* base = (const unsigned*)xw;   // row j starts at dword j*64
    float a0 = 0.f, a1 = 0.f;
    for (int p = s; p < e; p += 8) {
        int j[8];
        unsigned u[8];
#pragma unroll
        for (int q = 0; q < 8; ++q) {
            int pq = (p + q < e) ? p + q : p;
            j[q] = col[pq];
        }
#pragma unroll
        for (int q = 0; q < 8; ++q) u[q] = base[(size_t)j[q] * 64 + t];
        a0 += b2f_lo(u[0]);
        a1 += b2f_hi(u[0]);
#pragma unroll
        for (int q = 1; q < 8; ++q) {
            float mq = (p + q < e) ? 1.f : 0.f;
            a0 += mq * b2f_lo(u[q]);
            a1 += mq * b2f_hi(u[q]);
        }
    }
    float di = dinv[i];
    unsigned us = base[(size_t)i * 64 + t];
    float v0 = di * (a0 + b2f_lo(us)) + bias[t * 2];
    float v1 = di * (a1 + b2f_hi(us)) + bias[t * 2 + 1];
    if (do_elu) {
        v0 = (v0 > 0.f) ? v0 : (__expf(v0) - 1.f);
        v1 = (v1 > 0.f) ? v1 : (__expf(v1) - 1.f);
    }
    unsigned w = (unsigned)f2b(v0) | ((unsigned)f2b(v1) << 16);
    *(unsigned*)&hout[(size_t)i * F + t * 2] = w;
}

// ---------------- graph boundaries by binary search ----------------
__global__ __launch_bounds__(128) void k_gstart(const int* __restrict__ batch, int* __restrict__ gstart) {
    int g = threadIdx.x;
    if (g > NG) return;
    if (g == NG) { gstart[NG] = NN; return; }
    int lo = 0, hi = NN;
    while (lo < hi) { int mid = (lo + hi) >> 1; if (batch[mid] < g) lo = mid + 1; else hi = mid; }
    gstart[g] = lo;
}

// ---------------- mean pool (partial sums, atomic combine) ----------------
__global__ __launch_bounds__(128) void k_pool(const unsigned short* __restrict__ h,
                                              const int* __restrict__ gstart,
                                              float* __restrict__ poolsum) {
    int g = blockIdx.x >> 4, q = blockIdx.x & 15;
    int c = threadIdx.x;
    int s = gstart[g], e = gstart[g + 1];
    int n = e - s;
    int per = (n + 15) >> 4;
    int ss = s + q * per;
    int ee = min(ss + per, e);
    float acc = 0.f;
    for (int i = ss; i < ee; ++i) acc += b2f(h[(size_t)i * F + c]);
    atomicAdd(&poolsum[g * F + c], acc);
}

// ---------------- final MLP ----------------
__global__ __launch_bounds__(64) void k_mlp(const float* __restrict__ poolsum, const int* __restrict__ gstart,
                                            const float* __restrict__ stats,
                                            const float* __restrict__ fw1, const float* __restrict__ fb1,
                                            const float* __restrict__ fw2, const float* __restrict__ fb2,
                                            const float* __restrict__ fw3, const float* __restrict__ fb3,
                                            float* __restrict__ out) {
    __shared__ float gv[F + 8];
    __shared__ float h1[32];
    __shared__ float h2[16];
    int g = blockIdx.x, t = threadIdx.x;
    float cntf = fmaxf((float)(gstart[g + 1] - gstart[g]), 1.0f);
    for (int c = t; c < F; c += 64) gv[c] = poolsum[g * F + c] / cntf;
    if (t < 8) gv[F + t] = stats[g * 8 + t];
    __syncthreads();
    if (t < 32) {
        float a = fb1[t];
        for (int k = 0; k < F + 8; ++k) a += gv[k] * fw1[k * 32 + t];
        h1[t] = fmaxf(a, 0.f);
    }
    __syncthreads();
    if (t < 16) {
        float a = fb2[t];
        for (int k = 0; k < 32; ++k) a += h1[k] * fw2[k * 16 + t];
        h2[t] = fmaxf(a, 0.f);
    }
    __syncthreads();
    if (t == 0) {
        float a = fb3[0];
        for (int k = 0; k < 16; ++k) a += h2[k] * fw3[k];
        out[g] = a;
    }
}

extern "C" void kernel_launch(void* const* d_in, const int* in_sizes, int n_in,
                              void* d_out, int out_size, void* d_ws, size_t ws_size,
                              hipStream_t stream) {
    const float* x     = (const float*)d_in[0];
    const int*   ei    = (const int*)d_in[1];
    const int*   batch = (const int*)d_in[2];
    const float* stats = (const float*)d_in[3];
    const float* W1 = (const float*)d_in[4];
    const float* b1 = (const float*)d_in[5];
    const float* W2 = (const float*)d_in[6];
    const float* b2 = (const float*)d_in[7];
    const float* W3 = (const float*)d_in[8];
    const float* b3 = (const float*)d_in[9];
    const float* fw1 = (const float*)d_in[10];
    const float* fb1 = (const float*)d_in[11];
    const float* fw2 = (const float*)d_in[12];
    const float* fb2 = (const float*)d_in[13];
    const float* fw3 = (const float*)d_in[14];
    const float* fb3 = (const float*)d_in[15];
    float* out = (float*)d_out;

    const int* srcp = ei;
    const int* dstp = ei + NE;

    char* w = (char*)d_ws;
    size_t off = 0;
    auto take = [&](size_t bytes) -> char* {
        char* p = w + off;
        off += (bytes + 255) & ~size_t(255);
        return p;
    };
    int*   cnt       = (int*)take((size_t)NN * 4);
    int*   row_start = (int*)take((size_t)(NN + 1) * 4);
    int*   col       = (int*)take((size_t)NE * 4);
    float* dinv      = (float*)take((size_t)NN * 4);
    int*   gstart    = (int*)take((size_t)(NG + 1) * 4);
    float* poolsum   = (float*)take((size_t)NG * F * 4);
    int*   histg     = (int*)take((size_t)NBLK * NBUCK * 4);
    int*   offs      = (int*)take((size_t)NBLK * NBUCK * 4);
    int*   tot       = (int*)take((size_t)NBUCK * 4);
    int*   base      = (int*)take((size_t)(NBUCK + 1) * 4);
    int2*  pair      = (int2*)take((size_t)NE * 8);
    unsigned short* Wt   = (unsigned short*)take((size_t)F * F * 2);
    unsigned short* bufA = (unsigned short*)take((size_t)NN * F * 2);
    unsigned short* bufB = (unsigned short*)take((size_t)NN * F * 2);

    hipMemsetAsync(poolsum, 0, (size_t)NG * F * 4, stream);

    // CSR build: two-level counting sort, all writes dense or L2-local
    k_hist<<<NBLK, 256, 0, stream>>>(dstp, histg);
    k_boff<<<NBUCK, 64, 0, stream>>>(histg, offs, tot);
    k_scanb<<<1, 1024, 0, stream>>>(tot, base);
    k_place<<<NBLK, 256, 0, stream>>>(srcp, dstp, offs, base, pair);
    k_final<<<NBUCK, 256, 0, stream>>>(pair, base, cnt, dinv, row_start, col);
    k_gstart<<<1, 128, 0, stream>>>(batch, gstart);

    const int gemm_grid = (NN + 127) / 128;

    // layer 1 (fp32 input)
    k_wprep<<<64, 256, 0, stream>>>(W1, Wt);
    k_gemm_mfma<true><<<gemm_grid, 256, 0, stream>>>(x, Wt, dinv, bufA);
    k_spmm<<<NN, 64, 0, stream>>>(bufA, row_start, col, dinv, b1, bufB, 1);
    // layer 2
    k_wprep<<<64, 256, 0, stream>>>(W2, Wt);
    k_gemm_mfma<false><<<gemm_grid, 256, 0, stream>>>(bufB, Wt, dinv, bufA);
    k_spmm<<<NN, 64, 0, stream>>>(bufA, row_start, col, dinv, b2, bufB, 1);
    // layer 3
    k_wprep<<<64, 256, 0, stream>>>(W3, Wt);
    k_gemm_mfma<false><<<gemm_grid, 256, 0, stream>>>(bufB, Wt, dinv, bufA);
    k_spmm<<<NN, 64, 0, stream>>>(bufA, row_start, col, dinv, b3, bufB, 0);

    k_pool<<<NG * 16, F, 0, stream>>>(bufB, gstart, poolsum);
    k_mlp<<<NG, 64, 0, stream>>>(poolsum, gstart, stats, fw1, fb1, fw2, fb2, fw3, fb3, out);
}

// Round 9
// 397.040 us; speedup vs baseline: 3.9198x; 1.0186x over previous
//
#include <hip/hip_runtime.h>
#include <math.h>

#define NN 100000
#define NE 1600000
#define NG 64
#define F  128

constexpr int NBUCK = (NN + 127) / 128;     // 782 buckets of 128 nodes
constexpr int NBLK  = 64;                   // hist/place blocks
constexpr int EPB   = NE / NBLK;            // 25000 edges per block (exact)
constexpr int BCAP  = 3072;                 // LDS pair cap per bucket (mean 2046, sigma ~45)

typedef __bf16 bf16x8 __attribute__((ext_vector_type(8)));
typedef float  f32x4  __attribute__((ext_vector_type(4)));

__device__ __forceinline__ float b2f(unsigned short u) {
    union { unsigned i; float f; } v; v.i = ((unsigned)u) << 16; return v.f;
}
__device__ __forceinline__ float b2f_lo(unsigned u) {
    union { unsigned i; float f; } v; v.i = u << 16; return v.f;
}
__device__ __forceinline__ float b2f_hi(unsigned u) {
    union { unsigned i; float f; } v; v.i = u & 0xffff0000u; return v.f;
}
__device__ __forceinline__ unsigned short f2b(float f) {
    union { float f; unsigned i; } v; v.f = f;
    unsigned i = v.i;
    return (unsigned short)((i + 0x7fffu + ((i >> 16) & 1u)) >> 16);  // RNE
}

// ---------------- sort pipeline 1: per-block bucket histogram (LDS, dense write) --------
__global__ __launch_bounds__(256) void k_hist(const int* __restrict__ dst, int* __restrict__ histg) {
    __shared__ int h[NBUCK];
    int blk = blockIdx.x, t = threadIdx.x;
    for (int b = t; b < NBUCK; b += 256) h[b] = 0;
    __syncthreads();
    int s0 = blk * EPB, s1 = s0 + EPB;
    for (int e = s0 + t; e < s1; e += 256) {
        int d = __builtin_nontemporal_load(&dst[e]);
        atomicAdd(&h[d >> 7], 1);
    }
    __syncthreads();
    for (int b = t; b < NBUCK; b += 256) histg[blk * NBUCK + b] = h[b];
}

// ---------------- sort pipeline 2: per-bucket scan over blocks (1 wave) ----------------
__global__ __launch_bounds__(64) void k_boff(const int* __restrict__ histg, int* __restrict__ offs,
                                             int* __restrict__ tot) {
    int b = blockIdx.x, t = threadIdx.x;
    int v = histg[t * NBUCK + b];
    int incl = v;
#pragma unroll
    for (int d = 1; d < 64; d <<= 1) {
        int x = __shfl_up(incl, d);
        if (t >= d) incl += x;
    }
    offs[t * NBUCK + b] = incl - v;   // exclusive over blocks
    if (t == 63) tot[b] = incl;
}

// ---------------- sort pipeline 3: exclusive scan of bucket totals ----------------
__global__ __launch_bounds__(1024) void k_scanb(const int* __restrict__ tot, int* __restrict__ base) {
    __shared__ int sh[1024];
    int t = threadIdx.x;
    int v = (t < NBUCK) ? tot[t] : 0;
    sh[t] = v; __syncthreads();
    for (int d = 1; d < 1024; d <<= 1) {
        int x = (t >= d) ? sh[t - d] : 0;
        __syncthreads();
        sh[t] += x;
        __syncthreads();
    }
    if (t < NBUCK) base[t] = sh[t] - v;      // exclusive
    if (t == NBUCK - 1) base[NBUCK] = sh[t]; // = NE
}

// ---------------- sort pipeline 4: place (src,dst) pairs bucket-partitioned ----------------
__global__ __launch_bounds__(256) void k_place(const int* __restrict__ src, const int* __restrict__ dst,
                                               const int* __restrict__ offs, const int* __restrict__ base,
                                               int2* __restrict__ pair) {
    __shared__ int cur[NBUCK];
    int blk = blockIdx.x, t = threadIdx.x;
    for (int b = t; b < NBUCK; b += 256) cur[b] = base[b] + offs[blk * NBUCK + b];
    __syncthreads();
    int s0 = blk * EPB, s1 = s0 + EPB;
    for (int e = s0 + t; e < s1; e += 256) {
        int d = __builtin_nontemporal_load(&dst[e]);
        int s = __builtin_nontemporal_load(&src[e]);
        int pos = atomicAdd(&cur[d >> 7], 1);
        pair[pos] = make_int2(s, d);
    }
}

// ---------------- sort pipeline 5: per-bucket finalize ----------------
// Stages the bucket's pair slab in LDS; emits dinv/row_start densely and scatters
// col within an L2-resident ~8KB window. Everything written exactly once.
__global__ __launch_bounds__(256) void k_final(const int2* __restrict__ pair, const int* __restrict__ base,
                                               float* __restrict__ dinv,
                                               int* __restrict__ row_start, int* __restrict__ col) {
    __shared__ int2 lp[BCAP];
    __shared__ int c[128];
    __shared__ int loc[128];
    int b = blockIdx.x, t = threadIdx.x;
    int s0 = base[b], s1 = base[b + 1];
    int n = s1 - s0;
    bool lds_ok = (n <= BCAP);
    for (int i = t; i < 128; i += 256) c[i] = 0;
    __syncthreads();
    if (lds_ok) {
        for (int i = t; i < n; i += 256) {
            int2 sd = pair[s0 + i];
            lp[i] = sd;
            atomicAdd(&c[sd.y & 127], 1);
        }
    } else {
        for (int i = t; i < n; i += 256) atomicAdd(&c[pair[s0 + i].y & 127], 1);
    }
    __syncthreads();
    if (t == 0) {
        int run = 0;
        for (int i = 0; i < 128; ++i) { loc[i] = run; run += c[i]; }
    }
    __syncthreads();
    int g0 = b * 128;
    if (t < 128 && g0 + t < NN) {
        int deg = c[t];
        dinv[g0 + t] = rsqrtf((float)deg + 1.0f);
        row_start[g0 + t] = s0 + loc[t];
    }
    if (b == NBUCK - 1 && t == 0) row_start[NN] = NE;
    // reuse c[] as cursors
    if (t < 128) c[t] = loc[t];
    __syncthreads();
    if (lds_ok) {
        for (int i = t; i < n; i += 256) {
            int2 sd = lp[i];
            int pos = atomicAdd(&c[sd.y & 127], 1);
            col[s0 + pos] = sd.x;
        }
    } else {
        for (int i = t; i < n; i += 256) {
            int2 sd = pair[s0 + i];
            int pos = atomicAdd(&c[sd.y & 127], 1);
            col[s0 + pos] = sd.x;
        }
    }
}

// ---------------- W prep (all 3 layers): Wt[l][n][k] = bf16(Wl[k][n]) ----------------
__global__ __launch_bounds__(256) void k_wprep3(const float* __restrict__ W1, const float* __restrict__ W2,
                                                const float* __restrict__ W3, unsigned short* __restrict__ Wt) {
    int which = blockIdx.x >> 6;                 // 64 blocks per weight
    const float* W = (which == 0) ? W1 : (which == 1) ? W2 : W3;
    int idx = (blockIdx.x & 63) * 256 + threadIdx.x;   // 16384 per weight
    int k = idx >> 7, n = idx & 127;
    Wt[(size_t)which * F * F + n * F + k] = f2b(W[idx]);
}

// ---------------- MFMA GEMM: C[r,:] = dinv[r] * (A[r,:] @ W), bf16 out, fp32 acc ----------
template <bool FP32IN>
__global__ __launch_bounds__(256) void k_gemm_mfma(const void* __restrict__ Av,
                                                   const unsigned short* __restrict__ Wt,
                                                   const float* __restrict__ dinv,
                                                   unsigned short* __restrict__ C) {
    __shared__ unsigned short Ws[F * F];  // 32 KB, swizzled: byte ^= (n&7)<<4
    int tid = threadIdx.x;
    int wid = tid >> 6;
    int lane = tid & 63;
    int l15 = lane & 15, l4 = lane >> 4;
    int row0 = blockIdx.x * 128 + wid * 32;

    bf16x8 af[2][4];
#pragma unroll
    for (int mf = 0; mf < 2; ++mf) {
        int r = row0 + mf * 16 + l15;
        if (r > NN - 1) r = NN - 1;
        if (FP32IN) {
            const float* rp = (const float*)Av + (size_t)r * F;
#pragma unroll
            for (int ks = 0; ks < 4; ++ks) {
                float4 v0 = *(const float4*)(rp + ks * 32 + l4 * 8);
                float4 v1 = *(const float4*)(rp + ks * 32 + l4 * 8 + 4);
                bf16x8 a;
                a[0] = (__bf16)v0.x; a[1] = (__bf16)v0.y; a[2] = (__bf16)v0.z; a[3] = (__bf16)v0.w;
                a[4] = (__bf16)v1.x; a[5] = (__bf16)v1.y; a[6] = (__bf16)v1.z; a[7] = (__bf16)v1.w;
                af[mf][ks] = a;
            }
        } else {
            const unsigned short* rp = (const unsigned short*)Av + (size_t)r * F;
#pragma unroll
            for (int ks = 0; ks < 4; ++ks)
                af[mf][ks] = *(const bf16x8*)(rp + ks * 32 + l4 * 8);
        }
    }

#pragma unroll
    for (int p = 0; p < 8; ++p) {
        int idx16 = p * 256 + tid;          // 16-byte unit index, 2048 total
        int n = idx16 >> 4;
        float4 v = *(const float4*)((const char*)Wt + (size_t)idx16 * 16);
        *(float4*)((char*)Ws + (((unsigned)idx16 * 16) ^ (unsigned)((n & 7) << 4))) = v;
    }
    __syncthreads();

    f32x4 acc[2][8];
#pragma unroll
    for (int mf = 0; mf < 2; ++mf)
#pragma unroll
        for (int nf = 0; nf < 8; ++nf) acc[mf][nf] = (f32x4){0.f, 0.f, 0.f, 0.f};

#pragma unroll
    for (int ks = 0; ks < 4; ++ks) {
        bf16x8 bfr[8];
#pragma unroll
        for (int nf = 0; nf < 8; ++nf) {
            int n = nf * 16 + l15;
            unsigned byte = (unsigned)(n * 256 + ks * 64 + l4 * 16) ^ (unsigned)((n & 7) << 4);
            bfr[nf] = *(const bf16x8*)((const char*)Ws + byte);
        }
#pragma unroll
        for (int nf = 0; nf < 8; ++nf) {
            acc[0][nf] = __builtin_amdgcn_mfma_f32_16x16x32_bf16(af[0][ks], bfr[nf], acc[0][nf], 0, 0, 0);
            acc[1][nf] = __builtin_amdgcn_mfma_f32_16x16x32_bf16(af[1][ks], bfr[nf], acc[1][nf], 0, 0, 0);
        }
    }

#pragma unroll
    for (int mf = 0; mf < 2; ++mf)
#pragma unroll
        for (int reg = 0; reg < 4; ++reg) {
            int r = row0 + mf * 16 + l4 * 4 + reg;
            if (r < NN) {
                float di = dinv[r];
#pragma unroll
                for (int nf = 0; nf < 8; ++nf)
                    C[(size_t)r * F + nf * 16 + l15] = f2b(di * acc[mf][nf][reg]);
            }
        }
}

// ---------------- SpMM aggregation + bias + optional ELU (bf16 io, fp32 acc) ----------------
// xw rows pre-scaled by dinv. out[i] = dinv[i]*(sum_j xw'[j] + xw'[i]) + b.
// block = 1 node, 64 threads; thread t handles cols 2t,2t+1 (1 dword per lane).
// Edge loop 16-deep (avg degree = 16: most nodes finish in 1-2 iters; 16 gathers
// in flight per wave — round-8 profile: 8-deep = 3.8 TB/s, still MLP-limited).
__global__ __launch_bounds__(64) void k_spmm(const unsigned short* __restrict__ xw,
                                             const int* __restrict__ row_start,
                                             const int* __restrict__ col,
                                             const float* __restrict__ dinv,
                                             const float* __restrict__ bias,
                                             unsigned short* __restrict__ hout,
                                             int do_elu) {
    int i = blockIdx.x;
    int t = threadIdx.x;
    int s = row_start[i], e = row_start[i + 1];
    const unsigned* base = (const unsigned*)xw;   // row j starts at dword j*64
    float a0 = 0.f, a1 = 0.f;
    for (int p = s; p < e; p += 16) {
        int j[16];
        unsigned u[16];
#pragma unroll
        for (int q = 0; q < 16; ++q) {
            int pq = (p + q < e) ? p + q : p;
            j[q] = col[pq];
        }
#pragma unroll
        for (int q = 0; q < 16; ++q) u[q] = base[(unsigned)(j[q] * 64 + t)];
        a0 += b2f_lo(u[0]);
        a1 += b2f_hi(u[0]);
#pragma unroll
        for (int q = 1; q < 16; ++q) {
            float mq = (p + q < e) ? 1.f : 0.f;
            a0 += mq * b2f_lo(u[q]);
            a1 += mq * b2f_hi(u[q]);
        }
    }
    float di = dinv[i];
    unsigned us = base[(unsigned)(i * 64 + t)];
    float v0 = di * (a0 + b2f_lo(us)) + bias[t * 2];
    float v1 = di * (a1 + b2f_hi(us)) + bias[t * 2 + 1];
    if (do_elu) {
        v0 = (v0 > 0.f) ? v0 : (__expf(v0) - 1.f);
        v1 = (v1 > 0.f) ? v1 : (__expf(v1) - 1.f);
    }
    unsigned w = (unsigned)f2b(v0) | ((unsigned)f2b(v1) << 16);
    *(unsigned*)&hout[(size_t)i * F + t * 2] = w;
}

// ---------------- graph boundaries by binary search ----------------
__global__ __launch_bounds__(128) void k_gstart(const int* __restrict__ batch, int* __restrict__ gstart) {
    int g = threadIdx.x;
    if (g > NG) return;
    if (g == NG) { gstart[NG] = NN; return; }
    int lo = 0, hi = NN;
    while (lo < hi) { int mid = (lo + hi) >> 1; if (batch[mid] < g) lo = mid + 1; else hi = mid; }
    gstart[g] = lo;
}

// ---------------- mean pool (partial sums, atomic combine) ----------------
__global__ __launch_bounds__(128) void k_pool(const unsigned short* __restrict__ h,
                                              const int* __restrict__ gstart,
                                              float* __restrict__ poolsum) {
    int g = blockIdx.x >> 4, q = blockIdx.x & 15;
    int c = threadIdx.x;
    int s = gstart[g], e = gstart[g + 1];
    int n = e - s;
    int per = (n + 15) >> 4;
    int ss = s + q * per;
    int ee = min(ss + per, e);
    float acc = 0.f;
    for (int i = ss; i < ee; ++i) acc += b2f(h[(size_t)i * F + c]);
    atomicAdd(&poolsum[g * F + c], acc);
}

// ---------------- final MLP ----------------
__global__ __launch_bounds__(64) void k_mlp(const float* __restrict__ poolsum, const int* __restrict__ gstart,
                                            const float* __restrict__ stats,
                                            const float* __restrict__ fw1, const float* __restrict__ fb1,
                                            const float* __restrict__ fw2, const float* __restrict__ fb2,
                                            const float* __restrict__ fw3, const float* __restrict__ fb3,
                                            float* __restrict__ out) {
    __shared__ float gv[F + 8];
    __shared__ float h1[32];
    __shared__ float h2[16];
    int g = blockIdx.x, t = threadIdx.x;
    float cntf = fmaxf((float)(gstart[g + 1] - gstart[g]), 1.0f);
    for (int c = t; c < F; c += 64) gv[c] = poolsum[g * F + c] / cntf;
    if (t < 8) gv[F + t] = stats[g * 8 + t];
    __syncthreads();
    if (t < 32) {
        float a = fb1[t];
        for (int k = 0; k < F + 8; ++k) a += gv[k] * fw1[k * 32 + t];
        h1[t] = fmaxf(a, 0.f);
    }
    __syncthreads();
    if (t < 16) {
        float a = fb2[t];
        for (int k = 0; k < 32; ++k) a += h1[k] * fw2[k * 16 + t];
        h2[t] = fmaxf(a, 0.f);
    }
    __syncthreads();
    if (t == 0) {
        float a = fb3[0];
        for (int k = 0; k < 16; ++k) a += h2[k] * fw3[k];
        out[g] = a;
    }
}

extern "C" void kernel_launch(void* const* d_in, const int* in_sizes, int n_in,
                              void* d_out, int out_size, void* d_ws, size_t ws_size,
                              hipStream_t stream) {
    const float* x     = (const float*)d_in[0];
    const int*   ei    = (const int*)d_in[1];
    const int*   batch = (const int*)d_in[2];
    const float* stats = (const float*)d_in[3];
    const float* W1 = (const float*)d_in[4];
    const float* b1 = (const float*)d_in[5];
    const float* W2 = (const float*)d_in[6];
    const float* b2 = (const float*)d_in[7];
    const float* W3 = (const float*)d_in[8];
    const float* b3 = (const float*)d_in[9];
    const float* fw1 = (const float*)d_in[10];
    const float* fb1 = (const float*)d_in[11];
    const float* fw2 = (const float*)d_in[12];
    const float* fb2 = (const float*)d_in[13];
    const float* fw3 = (const float*)d_in[14];
    const float* fb3 = (const float*)d_in[15];
    float* out = (float*)d_out;

    const int* srcp = ei;
    const int* dstp = ei + NE;

    char* w = (char*)d_ws;
    size_t off = 0;
    auto take = [&](size_t bytes) -> char* {
        char* p = w + off;
        off += (bytes + 255) & ~size_t(255);
        return p;
    };
    int*   row_start = (int*)take((size_t)(NN + 1) * 4);
    int*   col       = (int*)take((size_t)NE * 4);
    float* dinv      = (float*)take((size_t)NN * 4);
    int*   gstart    = (int*)take((size_t)(NG + 1) * 4);
    float* poolsum   = (float*)take((size_t)NG * F * 4);
    int*   histg     = (int*)take((size_t)NBLK * NBUCK * 4);
    int*   offs      = (int*)take((size_t)NBLK * NBUCK * 4);
    int*   tot       = (int*)take((size_t)NBUCK * 4);
    int*   base      = (int*)take((size_t)(NBUCK + 1) * 4);
    int2*  pair      = (int2*)take((size_t)NE * 8);
    unsigned short* Wt   = (unsigned short*)take((size_t)3 * F * F * 2);
    unsigned short* bufA = (unsigned short*)take((size_t)NN * F * 2);
    unsigned short* bufB = (unsigned short*)take((size_t)NN * F * 2);

    hipMemsetAsync(poolsum, 0, (size_t)NG * F * 4, stream);

    // CSR build: two-level counting sort, all writes dense or L2-local
    k_hist<<<NBLK, 256, 0, stream>>>(dstp, histg);
    k_boff<<<NBUCK, 64, 0, stream>>>(histg, offs, tot);
    k_scanb<<<1, 1024, 0, stream>>>(tot, base);
    k_place<<<NBLK, 256, 0, stream>>>(srcp, dstp, offs, base, pair);
    k_final<<<NBUCK, 256, 0, stream>>>(pair, base, dinv, row_start, col);
    k_gstart<<<1, 128, 0, stream>>>(batch, gstart);
    k_wprep3<<<192, 256, 0, stream>>>(W1, W2, W3, Wt);

    const int gemm_grid = (NN + 127) / 128;

    // layer 1 (fp32 input)
    k_gemm_mfma<true><<<gemm_grid, 256, 0, stream>>>(x, Wt, dinv, bufA);
    k_spmm<<<NN, 64, 0, stream>>>(bufA, row_start, col, dinv, b1, bufB, 1);
    // layer 2
    k_gemm_mfma<false><<<gemm_grid, 256, 0, stream>>>(bufB, Wt + F * F, dinv, bufA);
    k_spmm<<<NN, 64, 0, stream>>>(bufA, row_start, col, dinv, b2, bufB, 1);
    // layer 3
    k_gemm_mfma<false><<<gemm_grid, 256, 0, stream>>>(bufB, Wt + 2 * F * F, dinv, bufA);
    k_spmm<<<NN, 64, 0, stream>>>(bufA, row_start, col, dinv, b3, bufB, 0);

    k_pool<<<NG * 16, F, 0, stream>>>(bufB, gstart, poolsum);
    k_mlp<<<NG, 64, 0, stream>>>(poolsum, gstart, stats, fw1, fb1, fw2, fb2, fw3, fb3, out);
}

// Round 10
// 287.707 us; speedup vs baseline: 5.4094x; 1.3800x over previous
//
#include <hip/hip_runtime.h>
#include <math.h>

#define NN 100000
#define NE 1600000
#define NG 64
#define F  128

constexpr int NBUCK = (NN + 127) / 128;     // 782 buckets of 128 nodes
constexpr int NBLK  = 1024;                 // hist/place blocks (r9: 64 -> occupancy 2%)
constexpr int EPB   = (NE + NBLK - 1) / NBLK;  // 1563 edges per block
constexpr int BCAP  = 3072;                 // LDS pair cap per bucket (mean 2046)

typedef __bf16 bf16x8 __attribute__((ext_vector_type(8)));
typedef float  f32x4  __attribute__((ext_vector_type(4)));

__device__ __forceinline__ float b2f(unsigned short u) {
    union { unsigned i; float f; } v; v.i = ((unsigned)u) << 16; return v.f;
}
__device__ __forceinline__ unsigned short f2b(float f) {
    union { float f; unsigned i; } v; v.f = f;
    unsigned i = v.i;
    return (unsigned short)((i + 0x7fffu + ((i >> 16) & 1u)) >> 16);  // RNE
}

// ---------------- sort pipeline 1: per-block bucket histogram (LDS, dense write) --------
__global__ __launch_bounds__(256) void k_hist(const int* __restrict__ dst, int* __restrict__ histg) {
    __shared__ int h[NBUCK];
    int blk = blockIdx.x, t = threadIdx.x;
    for (int b = t; b < NBUCK; b += 256) h[b] = 0;
    __syncthreads();
    int s0 = blk * EPB, s1 = min(s0 + EPB, NE);
    for (int e = s0 + t; e < s1; e += 256) {
        int d = __builtin_nontemporal_load(&dst[e]);
        atomicAdd(&h[d >> 7], 1);
    }
    __syncthreads();
    for (int b = t; b < NBUCK; b += 256) histg[(size_t)blk * NBUCK + b] = h[b];
}

// ---------------- sort pipeline 2: per-bucket scan over 1024 blocks ----------------
// offs is bucket-major (offs[b*NBLK+t]) so writes are dense/coalesced.
__global__ __launch_bounds__(1024) void k_boff(const int* __restrict__ histg, int* __restrict__ offs,
                                               int* __restrict__ tot) {
    __shared__ int sh[NBLK];
    int b = blockIdx.x, t = threadIdx.x;
    int v = histg[(size_t)t * NBUCK + b];
    sh[t] = v; __syncthreads();
    for (int d = 1; d < NBLK; d <<= 1) {
        int x = (t >= d) ? sh[t - d] : 0;
        __syncthreads();
        sh[t] += x;
        __syncthreads();
    }
    offs[(size_t)b * NBLK + t] = sh[t] - v;   // exclusive over blocks
    if (t == NBLK - 1) tot[b] = sh[t];
}

// ---------------- sort pipeline 3: exclusive scan of bucket totals ----------------
__global__ __launch_bounds__(1024) void k_scanb(const int* __restrict__ tot, int* __restrict__ base) {
    __shared__ int sh[1024];
    int t = threadIdx.x;
    int v = (t < NBUCK) ? tot[t] : 0;
    sh[t] = v; __syncthreads();
    for (int d = 1; d < 1024; d <<= 1) {
        int x = (t >= d) ? sh[t - d] : 0;
        __syncthreads();
        sh[t] += x;
        __syncthreads();
    }
    if (t < NBUCK) base[t] = sh[t] - v;      // exclusive
    if (t == NBUCK - 1) base[NBUCK] = sh[t]; // = NE
}

// ---------------- sort pipeline 4: place (src,dst) pairs bucket-partitioned ----------------
__global__ __launch_bounds__(256) void k_place(const int* __restrict__ src, const int* __restrict__ dst,
                                               const int* __restrict__ offs, const int* __restrict__ base,
                                               int2* __restrict__ pair) {
    __shared__ int cur[NBUCK];
    int blk = blockIdx.x, t = threadIdx.x;
    for (int b = t; b < NBUCK; b += 256) cur[b] = base[b] + offs[(size_t)b * NBLK + blk];
    __syncthreads();
    int s0 = blk * EPB, s1 = min(s0 + EPB, NE);
    for (int e = s0 + t; e < s1; e += 256) {
        int d = __builtin_nontemporal_load(&dst[e]);
        int s = __builtin_nontemporal_load(&src[e]);
        int pos = atomicAdd(&cur[d >> 7], 1);
        pair[pos] = make_int2(s, d);
    }
}

// ---------------- sort pipeline 5: per-bucket finalize ----------------
__global__ __launch_bounds__(256) void k_final(const int2* __restrict__ pair, const int* __restrict__ base,
                                               float* __restrict__ dinv,
                                               int* __restrict__ row_start, int* __restrict__ col) {
    __shared__ int2 lp[BCAP];
    __shared__ int c[128];
    __shared__ int loc[128];
    int b = blockIdx.x, t = threadIdx.x;
    int s0 = base[b], s1 = base[b + 1];
    int n = s1 - s0;
    bool lds_ok = (n <= BCAP);
    for (int i = t; i < 128; i += 256) c[i] = 0;
    __syncthreads();
    if (lds_ok) {
        for (int i = t; i < n; i += 256) {
            int2 sd = pair[s0 + i];
            lp[i] = sd;
            atomicAdd(&c[sd.y & 127], 1);
        }
    } else {
        for (int i = t; i < n; i += 256) atomicAdd(&c[pair[s0 + i].y & 127], 1);
    }
    __syncthreads();
    if (t == 0) {
        int run = 0;
        for (int i = 0; i < 128; ++i) { loc[i] = run; run += c[i]; }
    }
    __syncthreads();
    int g0 = b * 128;
    if (t < 128 && g0 + t < NN) {
        int deg = c[t];
        dinv[g0 + t] = rsqrtf((float)deg + 1.0f);
        row_start[g0 + t] = s0 + loc[t];
    }
    if (b == NBUCK - 1 && t == 0) row_start[NN] = NE;
    if (t < 128) c[t] = loc[t];
    __syncthreads();
    if (lds_ok) {
        for (int i = t; i < n; i += 256) {
            int2 sd = lp[i];
            int pos = atomicAdd(&c[sd.y & 127], 1);
            col[s0 + pos] = sd.x;
        }
    } else {
        for (int i = t; i < n; i += 256) {
            int2 sd = pair[s0 + i];
            int pos = atomicAdd(&c[sd.y & 127], 1);
            col[s0 + pos] = sd.x;
        }
    }
}

// ---------------- W prep (all 3 layers): Wt[l][n][k] = bf16(Wl[k][n]) ----------------
__global__ __launch_bounds__(256) void k_wprep3(const float* __restrict__ W1, const float* __restrict__ W2,
                                                const float* __restrict__ W3, unsigned short* __restrict__ Wt) {
    int which = blockIdx.x >> 6;                 // 64 blocks per weight
    const float* W = (which == 0) ? W1 : (which == 1) ? W2 : W3;
    int idx = (blockIdx.x & 63) * 256 + threadIdx.x;   // 16384 per weight
    int k = idx >> 7, n = idx & 127;
    Wt[(size_t)which * F * F + n * F + k] = f2b(W[idx]);
}

// ---------------- MFMA GEMM: C8[r,:] = fp8(dinv[r] * (A[r,:] @ W)), fp32 acc ----------
template <bool FP32IN>
__global__ __launch_bounds__(256) void k_gemm_mfma(const void* __restrict__ Av,
                                                   const unsigned short* __restrict__ Wt,
                                                   const float* __restrict__ dinv,
                                                   unsigned char* __restrict__ C8) {
    __shared__ unsigned short Ws[F * F];  // 32 KB, swizzled: byte ^= (n&7)<<4
    int tid = threadIdx.x;
    int wid = tid >> 6;
    int lane = tid & 63;
    int l15 = lane & 15, l4 = lane >> 4;
    int row0 = blockIdx.x * 128 + wid * 32;

    bf16x8 af[2][4];
#pragma unroll
    for (int mf = 0; mf < 2; ++mf) {
        int r = row0 + mf * 16 + l15;
        if (r > NN - 1) r = NN - 1;
        if (FP32IN) {
            const float* rp = (const float*)Av + (size_t)r * F;
#pragma unroll
            for (int ks = 0; ks < 4; ++ks) {
                float4 v0 = *(const float4*)(rp + ks * 32 + l4 * 8);
                float4 v1 = *(const float4*)(rp + ks * 32 + l4 * 8 + 4);
                bf16x8 a;
                a[0] = (__bf16)v0.x; a[1] = (__bf16)v0.y; a[2] = (__bf16)v0.z; a[3] = (__bf16)v0.w;
                a[4] = (__bf16)v1.x; a[5] = (__bf16)v1.y; a[6] = (__bf16)v1.z; a[7] = (__bf16)v1.w;
                af[mf][ks] = a;
            }
        } else {
            const unsigned short* rp = (const unsigned short*)Av + (size_t)r * F;
#pragma unroll
            for (int ks = 0; ks < 4; ++ks)
                af[mf][ks] = *(const bf16x8*)(rp + ks * 32 + l4 * 8);
        }
    }

#pragma unroll
    for (int p = 0; p < 8; ++p) {
        int idx16 = p * 256 + tid;          // 16-byte unit index, 2048 total
        int n = idx16 >> 4;
        float4 v = *(const float4*)((const char*)Wt + (size_t)idx16 * 16);
        *(float4*)((char*)Ws + (((unsigned)idx16 * 16) ^ (unsigned)((n & 7) << 4))) = v;
    }
    __syncthreads();

    f32x4 acc[2][8];
#pragma unroll
    for (int mf = 0; mf < 2; ++mf)
#pragma unroll
        for (int nf = 0; nf < 8; ++nf) acc[mf][nf] = (f32x4){0.f, 0.f, 0.f, 0.f};

#pragma unroll
    for (int ks = 0; ks < 4; ++ks) {
        bf16x8 bfr[8];
#pragma unroll
        for (int nf = 0; nf < 8; ++nf) {
            int n = nf * 16 + l15;
            unsigned byte = (unsigned)(n * 256 + ks * 64 + l4 * 16) ^ (unsigned)((n & 7) << 4);
            bfr[nf] = *(const bf16x8*)((const char*)Ws + byte);
        }
#pragma unroll
        for (int nf = 0; nf < 8; ++nf) {
            acc[0][nf] = __builtin_amdgcn_mfma_f32_16x16x32_bf16(af[0][ks], bfr[nf], acc[0][nf], 0, 0, 0);
            acc[1][nf] = __builtin_amdgcn_mfma_f32_16x16x32_bf16(af[1][ks], bfr[nf], acc[1][nf], 0, 0, 0);
        }
    }

    // write C as fp8 e4m3 (HW cvt). C/D layout: col = lane&15, row = (lane>>4)*4 + reg
#pragma unroll
    for (int mf = 0; mf < 2; ++mf)
#pragma unroll
        for (int reg = 0; reg < 4; ++reg) {
            int r = row0 + mf * 16 + l4 * 4 + reg;
            if (r < NN) {
                float di = dinv[r];
#pragma unroll
                for (int nf = 0; nf < 8; ++nf) {
                    float v = di * acc[mf][nf][reg];
                    int enc = __builtin_amdgcn_cvt_pk_fp8_f32(v, v, 0, false);
                    C8[(size_t)r * F + nf * 16 + l15] = (unsigned char)(enc & 0xff);
                }
            }
        }
}

// ---------------- SpMM aggregation (fp8 gather, fp32 acc, bf16 out) ----------------
// xw8 rows (128 B) pre-scaled by dinv. out[i] = dinv[i]*(sum_j xw'[j] + xw'[i]) + b.
// 64 threads = 2 edge slots x 32 lanes; lane covers 4 cols via one dword (4 fp8).
// 16 edges in flight (8 groups x 2 slots); slot-sum via shfl_xor(32).
__global__ __launch_bounds__(64) void k_spmm(const unsigned char* __restrict__ xw8,
                                             const int* __restrict__ row_start,
                                             const int* __restrict__ col,
                                             const float* __restrict__ dinv,
                                             const float* __restrict__ bias,
                                             unsigned short* __restrict__ hout,
                                             int do_elu) {
    int i = blockIdx.x;
    int t = threadIdx.x;
    int lc = t & 31;          // col quad: cols 4*lc .. 4*lc+3
    int slot = t >> 5;        // 0/1: which edge of the pair
    int s = row_start[i], e = row_start[i + 1];
    const unsigned* base = (const unsigned*)xw8;   // row j starts at dword j*32
    float a0 = 0.f, a1 = 0.f, a2 = 0.f, a3 = 0.f;
    for (int p = s; p < e; p += 16) {
        int j[8];
        unsigned u[8];
#pragma unroll
        for (int q = 0; q < 8; ++q) {
            int pe = p + q * 2 + slot;
            j[q] = col[pe < e ? pe : p];
        }
#pragma unroll
        for (int q = 0; q < 8; ++q) u[q] = base[(unsigned)(j[q] * 32 + lc)];
#pragma unroll
        for (int q = 0; q < 8; ++q) {
            int pe = p + q * 2 + slot;
            float m = (pe < e) ? 1.f : 0.f;
            auto lo = __builtin_amdgcn_cvt_pk_f32_fp8(u[q], false);
            auto hi = __builtin_amdgcn_cvt_pk_f32_fp8(u[q], true);
            a0 += m * lo[0]; a1 += m * lo[1]; a2 += m * hi[0]; a3 += m * hi[1];
        }
    }
    a0 += __shfl_xor(a0, 32);
    a1 += __shfl_xor(a1, 32);
    a2 += __shfl_xor(a2, 32);
    a3 += __shfl_xor(a3, 32);
    float di = dinv[i];
    unsigned us = base[(unsigned)(i * 32 + lc)];
    auto slo = __builtin_amdgcn_cvt_pk_f32_fp8(us, false);
    auto shi = __builtin_amdgcn_cvt_pk_f32_fp8(us, true);
    float4 b4 = *(const float4*)&bias[lc * 4];
    float v0 = di * (a0 + slo[0]) + b4.x;
    float v1 = di * (a1 + slo[1]) + b4.y;
    float v2 = di * (a2 + shi[0]) + b4.z;
    float v3 = di * (a3 + shi[1]) + b4.w;
    if (do_elu) {
        v0 = (v0 > 0.f) ? v0 : (__expf(v0) - 1.f);
        v1 = (v1 > 0.f) ? v1 : (__expf(v1) - 1.f);
        v2 = (v2 > 0.f) ? v2 : (__expf(v2) - 1.f);
        v3 = (v3 > 0.f) ? v3 : (__expf(v3) - 1.f);
    }
    if (slot == 0) {
        ushort4 o;
        o.x = f2b(v0); o.y = f2b(v1); o.z = f2b(v2); o.w = f2b(v3);
        *(ushort4*)&hout[(size_t)i * F + lc * 4] = o;
    }
}

// ---------------- graph boundaries by binary search ----------------
__global__ __launch_bounds__(128) void k_gstart(const int* __restrict__ batch, int* __restrict__ gstart) {
    int g = threadIdx.x;
    if (g > NG) return;
    if (g == NG) { gstart[NG] = NN; return; }
    int lo = 0, hi = NN;
    while (lo < hi) { int mid = (lo + hi) >> 1; if (batch[mid] < g) lo = mid + 1; else hi = mid; }
    gstart[g] = lo;
}

// ---------------- mean pool (partial sums, atomic combine) ----------------
__global__ __launch_bounds__(128) void k_pool(const unsigned short* __restrict__ h,
                                              const int* __restrict__ gstart,
                                              float* __restrict__ poolsum) {
    int g = blockIdx.x >> 4, q = blockIdx.x & 15;
    int c = threadIdx.x;
    int s = gstart[g], e = gstart[g + 1];
    int n = e - s;
    int per = (n + 15) >> 4;
    int ss = s + q * per;
    int ee = min(ss + per, e);
    float acc = 0.f;
    for (int i = ss; i < ee; ++i) acc += b2f(h[(size_t)i * F + c]);
    atomicAdd(&poolsum[g * F + c], acc);
}

// ---------------- final MLP ----------------
__global__ __launch_bounds__(64) void k_mlp(const float* __restrict__ poolsum, const int* __restrict__ gstart,
                                            const float* __restrict__ stats,
                                            const float* __restrict__ fw1, const float* __restrict__ fb1,
                                            const float* __restrict__ fw2, const float* __restrict__ fb2,
                                            const float* __restrict__ fw3, const float* __restrict__ fb3,
                                            float* __restrict__ out) {
    __shared__ float gv[F + 8];
    __shared__ float h1[32];
    __shared__ float h2[16];
    int g = blockIdx.x, t = threadIdx.x;
    float cntf = fmaxf((float)(gstart[g + 1] - gstart[g]), 1.0f);
    for (int c = t; c < F; c += 64) gv[c] = poolsum[g * F + c] / cntf;
    if (t < 8) gv[F + t] = stats[g * 8 + t];
    __syncthreads();
    if (t < 32) {
        float a = fb1[t];
        for (int k = 0; k < F + 8; ++k) a += gv[k] * fw1[k * 32 + t];
        h1[t] = fmaxf(a, 0.f);
    }
    __syncthreads();
    if (t < 16) {
        float a = fb2[t];
        for (int k = 0; k < 32; ++k) a += h1[k] * fw2[k * 16 + t];
        h2[t] = fmaxf(a, 0.f);
    }
    __syncthreads();
    if (t == 0) {
        float a = fb3[0];
        for (int k = 0; k < 16; ++k) a += h2[k] * fw3[k];
        out[g] = a;
    }
}

extern "C" void kernel_launch(void* const* d_in, const int* in_sizes, int n_in,
                              void* d_out, int out_size, void* d_ws, size_t ws_size,
                              hipStream_t stream) {
    const float* x     = (const float*)d_in[0];
    const int*   ei    = (const int*)d_in[1];
    const int*   batch = (const int*)d_in[2];
    const float* stats = (const float*)d_in[3];
    const float* W1 = (const float*)d_in[4];
    const float* b1 = (const float*)d_in[5];
    const float* W2 = (const float*)d_in[6];
    const float* b2 = (const float*)d_in[7];
    const float* W3 = (const float*)d_in[8];
    const float* b3 = (const float*)d_in[9];
    const float* fw1 = (const float*)d_in[10];
    const float* fb1 = (const float*)d_in[11];
    const float* fw2 = (const float*)d_in[12];
    const float* fb2 = (const float*)d_in[13];
    const float* fw3 = (const float*)d_in[14];
    const float* fb3 = (const float*)d_in[15];
    float* out = (float*)d_out;

    const int* srcp = ei;
    const int* dstp = ei + NE;

    char* w = (char*)d_ws;
    size_t off = 0;
    auto take = [&](size_t bytes) -> char* {
        char* p = w + off;
        off += (bytes + 255) & ~size_t(255);
        return p;
    };
    int*   row_start = (int*)take((size_t)(NN + 1) * 4);
    int*   col       = (int*)take((size_t)NE * 4);
    float* dinv      = (float*)take((size_t)NN * 4);
    int*   gstart    = (int*)take((size_t)(NG + 1) * 4);
    float* poolsum   = (float*)take((size_t)NG * F * 4);
    int*   histg     = (int*)take((size_t)NBLK * NBUCK * 4);
    int*   offs      = (int*)take((size_t)NBUCK * NBLK * 4);
    int*   tot       = (int*)take((size_t)NBUCK * 4);
    int*   base      = (int*)take((size_t)(NBUCK + 1) * 4);
    int2*  pair      = (int2*)take((size_t)NE * 8);
    unsigned short* Wt   = (unsigned short*)take((size_t)3 * F * F * 2);
    unsigned char*  bufA = (unsigned char*)take((size_t)NN * F);       // fp8 xw
    unsigned short* bufB = (unsigned short*)take((size_t)NN * F * 2);  // bf16 h

    hipMemsetAsync(poolsum, 0, (size_t)NG * F * 4, stream);

    // CSR build: two-level counting sort, all writes dense or L2-local
    k_hist<<<NBLK, 256, 0, stream>>>(dstp, histg);
    k_boff<<<NBUCK, NBLK, 0, stream>>>(histg, offs, tot);
    k_scanb<<<1, 1024, 0, stream>>>(tot, base);
    k_place<<<NBLK, 256, 0, stream>>>(srcp, dstp, offs, base, pair);
    k_final<<<NBUCK, 256, 0, stream>>>(pair, base, dinv, row_start, col);
    k_gstart<<<1, 128, 0, stream>>>(batch, gstart);
    k_wprep3<<<192, 256, 0, stream>>>(W1, W2, W3, Wt);

    const int gemm_grid = (NN + 127) / 128;

    // layer 1 (fp32 input)
    k_gemm_mfma<true><<<gemm_grid, 256, 0, stream>>>(x, Wt, dinv, bufA);
    k_spmm<<<NN, 64, 0, stream>>>(bufA, row_start, col, dinv, b1, bufB, 1);
    // layer 2
    k_gemm_mfma<false><<<gemm_grid, 256, 0, stream>>>(bufB, Wt + F * F, dinv, bufA);
    k_spmm<<<NN, 64, 0, stream>>>(bufA, row_start, col, dinv, b2, bufB, 1);
    // layer 3
    k_gemm_mfma<false><<<gemm_grid, 256, 0, stream>>>(bufB, Wt + 2 * F * F, dinv, bufA);
    k_spmm<<<NN, 64, 0, stream>>>(bufA, row_start, col, dinv, b3, bufB, 0);

    k_pool<<<NG * 16, F, 0, stream>>>(bufB, gstart, poolsum);
    k_mlp<<<NG, 64, 0, stream>>>(poolsum, gstart, stats, fw1, fb1, fw2, fb2, fw3, fb3, out);
}

// Round 11
// 276.442 us; speedup vs baseline: 5.6299x; 1.0408x over previous
//
#include <hip/hip_runtime.h>
#include <math.h>

#define NN 100000
#define NE 1600000
#define NG 64
#define F  128

constexpr int NBUCK = (NN + 127) / 128;     // 782 buckets of 128 nodes
constexpr int NBLK  = 256;                  // hist/place blocks: 1/CU, 8 edges/bucket/blk
constexpr int EPB   = (NE + NBLK - 1) / NBLK;  // 6250 edges per block
constexpr int BCAP  = 3072;                 // LDS packed-pair cap per bucket (mean 2046)

typedef __bf16 bf16x8 __attribute__((ext_vector_type(8)));
typedef float  f32x4  __attribute__((ext_vector_type(4)));

__device__ __forceinline__ float b2f(unsigned short u) {
    union { unsigned i; float f; } v; v.i = ((unsigned)u) << 16; return v.f;
}
__device__ __forceinline__ unsigned short f2b(float f) {
    union { float f; unsigned i; } v; v.f = f;
    unsigned i = v.i;
    return (unsigned short)((i + 0x7fffu + ((i >> 16) & 1u)) >> 16);  // RNE
}

// ---------------- sort pipeline 1: per-block bucket histogram (LDS, dense write) --------
__global__ __launch_bounds__(256) void k_hist(const int* __restrict__ dst, int* __restrict__ histg) {
    __shared__ int h[NBUCK];
    int blk = blockIdx.x, t = threadIdx.x;
    for (int b = t; b < NBUCK; b += 256) h[b] = 0;
    __syncthreads();
    int s0 = blk * EPB, s1 = min(s0 + EPB, NE);
    for (int e = s0 + t; e < s1; e += 256) {
        int d = __builtin_nontemporal_load(&dst[e]);
        atomicAdd(&h[d >> 7], 1);
    }
    __syncthreads();
    for (int b = t; b < NBUCK; b += 256) histg[(size_t)blk * NBUCK + b] = h[b];
}

// ---------------- sort pipeline 2: per-bucket scan over NBLK blocks ----------------
// offs is bucket-major (offs[b*NBLK+t]) so writes are dense/coalesced.
__global__ __launch_bounds__(NBLK) void k_boff(const int* __restrict__ histg, int* __restrict__ offs,
                                               int* __restrict__ tot) {
    __shared__ int sh[NBLK];
    int b = blockIdx.x, t = threadIdx.x;
    int v = histg[(size_t)t * NBUCK + b];
    sh[t] = v; __syncthreads();
    for (int d = 1; d < NBLK; d <<= 1) {
        int x = (t >= d) ? sh[t - d] : 0;
        __syncthreads();
        sh[t] += x;
        __syncthreads();
    }
    offs[(size_t)b * NBLK + t] = sh[t] - v;   // exclusive over blocks
    if (t == NBLK - 1) tot[b] = sh[t];
}

// ---------------- sort pipeline 3: exclusive scan of bucket totals ----------------
__global__ __launch_bounds__(1024) void k_scanb(const int* __restrict__ tot, int* __restrict__ base) {
    __shared__ int sh[1024];
    int t = threadIdx.x;
    int v = (t < NBUCK) ? tot[t] : 0;
    sh[t] = v; __syncthreads();
    for (int d = 1; d < 1024; d <<= 1) {
        int x = (t >= d) ? sh[t - d] : 0;
        __syncthreads();
        sh[t] += x;
        __syncthreads();
    }
    if (t < NBUCK) base[t] = sh[t] - v;      // exclusive
    if (t == NBUCK - 1) base[NBUCK] = sh[t]; // = NE
}

// ---------------- sort pipeline 4: place packed (src<<7|local) bucket-partitioned --------
// 4B per edge (halves r10's pair traffic); 8 edges x 4B = 32B per bucket-segment per
// block -> ~2 concurrent blocks per 64B line (r10 NBLK=1024: 4 -> WRITE 45.6MB).
__global__ __launch_bounds__(256) void k_place(const int* __restrict__ src, const int* __restrict__ dst,
                                               const int* __restrict__ offs, const int* __restrict__ base,
                                               unsigned* __restrict__ pair) {
    __shared__ int cur[NBUCK];
    int blk = blockIdx.x, t = threadIdx.x;
    for (int b = t; b < NBUCK; b += 256) cur[b] = base[b] + offs[(size_t)b * NBLK + blk];
    __syncthreads();
    int s0 = blk * EPB, s1 = min(s0 + EPB, NE);
    for (int e = s0 + t; e < s1; e += 256) {
        int d = __builtin_nontemporal_load(&dst[e]);
        int s = __builtin_nontemporal_load(&src[e]);
        int pos = atomicAdd(&cur[d >> 7], 1);
        pair[pos] = ((unsigned)s << 7) | (unsigned)(d & 127);
    }
}

// ---------------- sort pipeline 5: per-bucket finalize ----------------
__global__ __launch_bounds__(256) void k_final(const unsigned* __restrict__ pair, const int* __restrict__ base,
                                               float* __restrict__ dinv,
                                               int* __restrict__ row_start, int* __restrict__ col) {
    __shared__ unsigned lp[BCAP];
    __shared__ int c[128];
    __shared__ int loc[128];
    int b = blockIdx.x, t = threadIdx.x;
    int s0 = base[b], s1 = base[b + 1];
    int n = s1 - s0;
    bool lds_ok = (n <= BCAP);
    for (int i = t; i < 128; i += 256) c[i] = 0;
    __syncthreads();
    if (lds_ok) {
        for (int i = t; i < n; i += 256) {
            unsigned v = pair[s0 + i];
            lp[i] = v;
            atomicAdd(&c[v & 127u], 1);
        }
    } else {
        for (int i = t; i < n; i += 256) atomicAdd(&c[pair[s0 + i] & 127u], 1);
    }
    __syncthreads();
    if (t == 0) {
        int run = 0;
        for (int i = 0; i < 128; ++i) { loc[i] = run; run += c[i]; }
    }
    __syncthreads();
    int g0 = b * 128;
    if (t < 128 && g0 + t < NN) {
        int deg = c[t];
        dinv[g0 + t] = rsqrtf((float)deg + 1.0f);
        row_start[g0 + t] = s0 + loc[t];
    }
    if (b == NBUCK - 1 && t == 0) row_start[NN] = NE;
    if (t < 128) c[t] = loc[t];
    __syncthreads();
    if (lds_ok) {
        for (int i = t; i < n; i += 256) {
            unsigned v = lp[i];
            int pos = atomicAdd(&c[v & 127u], 1);
            col[s0 + pos] = (int)(v >> 7);
        }
    } else {
        for (int i = t; i < n; i += 256) {
            unsigned v = pair[s0 + i];
            int pos = atomicAdd(&c[v & 127u], 1);
            col[s0 + pos] = (int)(v >> 7);
        }
    }
}

// ---------------- W prep (all 3 layers): Wt[l][n][k] = bf16(Wl[k][n]) ----------------
__global__ __launch_bounds__(256) void k_wprep3(const float* __restrict__ W1, const float* __restrict__ W2,
                                                const float* __restrict__ W3, unsigned short* __restrict__ Wt) {
    int which = blockIdx.x >> 6;                 // 64 blocks per weight
    const float* W = (which == 0) ? W1 : (which == 1) ? W2 : W3;
    int idx = (blockIdx.x & 63) * 256 + threadIdx.x;   // 16384 per weight
    int k = idx >> 7, n = idx & 127;
    Wt[(size_t)which * F * F + n * F + k] = f2b(W[idx]);
}

// ---------------- MFMA GEMM: C8[r,:] = fp8(dinv[r] * (A[r,:] @ W)), fp32 acc ----------
template <bool FP32IN>
__global__ __launch_bounds__(256) void k_gemm_mfma(const void* __restrict__ Av,
                                                   const unsigned short* __restrict__ Wt,
                                                   const float* __restrict__ dinv,
                                                   unsigned char* __restrict__ C8) {
    __shared__ unsigned short Ws[F * F];  // 32 KB, swizzled: byte ^= (n&7)<<4
    int tid = threadIdx.x;
    int wid = tid >> 6;
    int lane = tid & 63;
    int l15 = lane & 15, l4 = lane >> 4;
    int row0 = blockIdx.x * 128 + wid * 32;

    bf16x8 af[2][4];
#pragma unroll
    for (int mf = 0; mf < 2; ++mf) {
        int r = row0 + mf * 16 + l15;
        if (r > NN - 1) r = NN - 1;
        if (FP32IN) {
            const float* rp = (const float*)Av + (size_t)r * F;
#pragma unroll
            for (int ks = 0; ks < 4; ++ks) {
                float4 v0 = *(const float4*)(rp + ks * 32 + l4 * 8);
                float4 v1 = *(const float4*)(rp + ks * 32 + l4 * 8 + 4);
                bf16x8 a;
                a[0] = (__bf16)v0.x; a[1] = (__bf16)v0.y; a[2] = (__bf16)v0.z; a[3] = (__bf16)v0.w;
                a[4] = (__bf16)v1.x; a[5] = (__bf16)v1.y; a[6] = (__bf16)v1.z; a[7] = (__bf16)v1.w;
                af[mf][ks] = a;
            }
        } else {
            const unsigned short* rp = (const unsigned short*)Av + (size_t)r * F;
#pragma unroll
            for (int ks = 0; ks < 4; ++ks)
                af[mf][ks] = *(const bf16x8*)(rp + ks * 32 + l4 * 8);
        }
    }

#pragma unroll
    for (int p = 0; p < 8; ++p) {
        int idx16 = p * 256 + tid;          // 16-byte unit index, 2048 total
        int n = idx16 >> 4;
        float4 v = *(const float4*)((const char*)Wt + (size_t)idx16 * 16);
        *(float4*)((char*)Ws + (((unsigned)idx16 * 16) ^ (unsigned)((n & 7) << 4))) = v;
    }
    __syncthreads();

    f32x4 acc[2][8];
#pragma unroll
    for (int mf = 0; mf < 2; ++mf)
#pragma unroll
        for (int nf = 0; nf < 8; ++nf) acc[mf][nf] = (f32x4){0.f, 0.f, 0.f, 0.f};

#pragma unroll
    for (int ks = 0; ks < 4; ++ks) {
        bf16x8 bfr[8];
#pragma unroll
        for (int nf = 0; nf < 8; ++nf) {
            int n = nf * 16 + l15;
            unsigned byte = (unsigned)(n * 256 + ks * 64 + l4 * 16) ^ (unsigned)((n & 7) << 4);
            bfr[nf] = *(const bf16x8*)((const char*)Ws + byte);
        }
#pragma unroll
        for (int nf = 0; nf < 8; ++nf) {
            acc[0][nf] = __builtin_amdgcn_mfma_f32_16x16x32_bf16(af[0][ks], bfr[nf], acc[0][nf], 0, 0, 0);
            acc[1][nf] = __builtin_amdgcn_mfma_f32_16x16x32_bf16(af[1][ks], bfr[nf], acc[1][nf], 0, 0, 0);
        }
    }

    // write C as fp8 e4m3 (HW cvt). C/D layout: col = lane&15, row = (lane>>4)*4 + reg
#pragma unroll
    for (int mf = 0; mf < 2; ++mf)
#pragma unroll
        for (int reg = 0; reg < 4; ++reg) {
            int r = row0 + mf * 16 + l4 * 4 + reg;
            if (r < NN) {
                float di = dinv[r];
#pragma unroll
                for (int nf = 0; nf < 8; ++nf) {
                    float v = di * acc[mf][nf][reg];
                    int enc = __builtin_amdgcn_cvt_pk_fp8_f32(v, v, 0, false);
                    C8[(size_t)r * F + nf * 16 + l15] = (unsigned char)(enc & 0xff);
                }
            }
        }
}

// ---------------- SpMM aggregation (fp8 gather, fp32 acc, bf16 out) ----------------
// xw8 rows (128 B) pre-scaled by dinv. out[i] = dinv[i]*(sum_j xw'[j] + xw'[i]) + b.
// 64 threads = 2 edge slots x 32 lanes; lane covers 4 cols via one dword (4 fp8).
// 16 edges in flight (8 groups x 2 slots); slot-sum via shfl_xor(32).
__global__ __launch_bounds__(64) void k_spmm(const unsigned char* __restrict__ xw8,
                                             const int* __restrict__ row_start,
                                             const int* __restrict__ col,
                                             const float* __restrict__ dinv,
                                             const float* __restrict__ bias,
                                             unsigned short* __restrict__ hout,
                                             int do_elu) {
    int i = blockIdx.x;
    int t = threadIdx.x;
    int lc = t & 31;          // col quad: cols 4*lc .. 4*lc+3
    int slot = t >> 5;        // 0/1: which edge of the pair
    int s = row_start[i], e = row_start[i + 1];
    const unsigned* base = (const unsigned*)xw8;   // row j starts at dword j*32
    float a0 = 0.f, a1 = 0.f, a2 = 0.f, a3 = 0.f;
    for (int p = s; p < e; p += 16) {
        int j[8];
        unsigned u[8];
#pragma unroll
        for (int q = 0; q < 8; ++q) {
            int pe = p + q * 2 + slot;
            j[q] = col[pe < e ? pe : p];
        }
#pragma unroll
        for (int q = 0; q < 8; ++q) u[q] = base[(unsigned)(j[q] * 32 + lc)];
#pragma unroll
        for (int q = 0; q < 8; ++q) {
            int pe = p + q * 2 + slot;
            float m = (pe < e) ? 1.f : 0.f;
            auto lo = __builtin_amdgcn_cvt_pk_f32_fp8(u[q], false);
            auto hi = __builtin_amdgcn_cvt_pk_f32_fp8(u[q], true);
            a0 += m * lo[0]; a1 += m * lo[1]; a2 += m * hi[0]; a3 += m * hi[1];
        }
    }
    a0 += __shfl_xor(a0, 32);
    a1 += __shfl_xor(a1, 32);
    a2 += __shfl_xor(a2, 32);
    a3 += __shfl_xor(a3, 32);
    float di = dinv[i];
    unsigned us = base[(unsigned)(i * 32 + lc)];
    auto slo = __builtin_amdgcn_cvt_pk_f32_fp8(us, false);
    auto shi = __builtin_amdgcn_cvt_pk_f32_fp8(us, true);
    float4 b4 = *(const float4*)&bias[lc * 4];
    float v0 = di * (a0 + slo[0]) + b4.x;
    float v1 = di * (a1 + slo[1]) + b4.y;
    float v2 = di * (a2 + shi[0]) + b4.z;
    float v3 = di * (a3 + shi[1]) + b4.w;
    if (do_elu) {
        v0 = (v0 > 0.f) ? v0 : (__expf(v0) - 1.f);
        v1 = (v1 > 0.f) ? v1 : (__expf(v1) - 1.f);
        v2 = (v2 > 0.f) ? v2 : (__expf(v2) - 1.f);
        v3 = (v3 > 0.f) ? v3 : (__expf(v3) - 1.f);
    }
    if (slot == 0) {
        ushort4 o;
        o.x = f2b(v0); o.y = f2b(v1); o.z = f2b(v2); o.w = f2b(v3);
        *(ushort4*)&hout[(size_t)i * F + lc * 4] = o;
    }
}

// ---------------- graph boundaries by binary search ----------------
__global__ __launch_bounds__(128) void k_gstart(const int* __restrict__ batch, int* __restrict__ gstart) {
    int g = threadIdx.x;
    if (g > NG) return;
    if (g == NG) { gstart[NG] = NN; return; }
    int lo = 0, hi = NN;
    while (lo < hi) { int mid = (lo + hi) >> 1; if (batch[mid] < g) lo = mid + 1; else hi = mid; }
    gstart[g] = lo;
}

// ---------------- mean pool (partial sums, atomic combine) ----------------
__global__ __launch_bounds__(128) void k_pool(const unsigned short* __restrict__ h,
                                              const int* __restrict__ gstart,
                                              float* __restrict__ poolsum) {
    int g = blockIdx.x >> 4, q = blockIdx.x & 15;
    int c = threadIdx.x;
    int s = gstart[g], e = gstart[g + 1];
    int n = e - s;
    int per = (n + 15) >> 4;
    int ss = s + q * per;
    int ee = min(ss + per, e);
    float acc = 0.f;
    for (int i = ss; i < ee; ++i) acc += b2f(h[(size_t)i * F + c]);
    atomicAdd(&poolsum[g * F + c], acc);
}

// ---------------- final MLP ----------------
__global__ __launch_bounds__(64) void k_mlp(const float* __restrict__ poolsum, const int* __restrict__ gstart,
                                            const float* __restrict__ stats,
                                            const float* __restrict__ fw1, const float* __restrict__ fb1,
                                            const float* __restrict__ fw2, const float* __restrict__ fb2,
                                            const float* __restrict__ fw3, const float* __restrict__ fb3,
                                            float* __restrict__ out) {
    __shared__ float gv[F + 8];
    __shared__ float h1[32];
    __shared__ float h2[16];
    int g = blockIdx.x, t = threadIdx.x;
    float cntf = fmaxf((float)(gstart[g + 1] - gstart[g]), 1.0f);
    for (int c = t; c < F; c += 64) gv[c] = poolsum[g * F + c] / cntf;
    if (t < 8) gv[F + t] = stats[g * 8 + t];
    __syncthreads();
    if (t < 32) {
        float a = fb1[t];
        for (int k = 0; k < F + 8; ++k) a += gv[k] * fw1[k * 32 + t];
        h1[t] = fmaxf(a, 0.f);
    }
    __syncthreads();
    if (t < 16) {
        float a = fb2[t];
        for (int k = 0; k < 32; ++k) a += h1[k] * fw2[k * 16 + t];
        h2[t] = fmaxf(a, 0.f);
    }
    __syncthreads();
    if (t == 0) {
        float a = fb3[0];
        for (int k = 0; k < 16; ++k) a += h2[k] * fw3[k];
        out[g] = a;
    }
}

extern "C" void kernel_launch(void* const* d_in, const int* in_sizes, int n_in,
                              void* d_out, int out_size, void* d_ws, size_t ws_size,
                              hipStream_t stream) {
    const float* x     = (const float*)d_in[0];
    const int*   ei    = (const int*)d_in[1];
    const int*   batch = (const int*)d_in[2];
    const float* stats = (const float*)d_in[3];
    const float* W1 = (const float*)d_in[4];
    const float* b1 = (const float*)d_in[5];
    const float* W2 = (const float*)d_in[6];
    const float* b2 = (const float*)d_in[7];
    const float* W3 = (const float*)d_in[8];
    const float* b3 = (const float*)d_in[9];
    const float* fw1 = (const float*)d_in[10];
    const float* fb1 = (const float*)d_in[11];
    const float* fw2 = (const float*)d_in[12];
    const float* fb2 = (const float*)d_in[13];
    const float* fw3 = (const float*)d_in[14];
    const float* fb3 = (const float*)d_in[15];
    float* out = (float*)d_out;

    const int* srcp = ei;
    const int* dstp = ei + NE;

    char* w = (char*)d_ws;
    size_t off = 0;
    auto take = [&](size_t bytes) -> char* {
        char* p = w + off;
        off += (bytes + 255) & ~size_t(255);
        return p;
    };
    int*   row_start = (int*)take((size_t)(NN + 1) * 4);
    int*   col       = (int*)take((size_t)NE * 4);
    float* dinv      = (float*)take((size_t)NN * 4);
    int*   gstart    = (int*)take((size_t)(NG + 1) * 4);
    float* poolsum   = (float*)take((size_t)NG * F * 4);
    int*   histg     = (int*)take((size_t)NBLK * NBUCK * 4);
    int*   offs      = (int*)take((size_t)NBUCK * NBLK * 4);
    int*   tot       = (int*)take((size_t)NBUCK * 4);
    int*   base      = (int*)take((size_t)(NBUCK + 1) * 4);
    unsigned* pair   = (unsigned*)take((size_t)NE * 4);
    unsigned short* Wt   = (unsigned short*)take((size_t)3 * F * F * 2);
    unsigned char*  bufA = (unsigned char*)take((size_t)NN * F);       // fp8 xw
    unsigned short* bufB = (unsigned short*)take((size_t)NN * F * 2);  // bf16 h

    hipMemsetAsync(poolsum, 0, (size_t)NG * F * 4, stream);

    // CSR build: two-level counting sort, all writes dense or L2-local
    k_hist<<<NBLK, 256, 0, stream>>>(dstp, histg);
    k_boff<<<NBUCK, NBLK, 0, stream>>>(histg, offs, tot);
    k_scanb<<<1, 1024, 0, stream>>>(tot, base);
    k_place<<<NBLK, 256, 0, stream>>>(srcp, dstp, offs, base, pair);
    k_final<<<NBUCK, 256, 0, stream>>>(pair, base, dinv, row_start, col);
    k_gstart<<<1, 128, 0, stream>>>(batch, gstart);
    k_wprep3<<<192, 256, 0, stream>>>(W1, W2, W3, Wt);

    const int gemm_grid = (NN + 127) / 128;

    // layer 1 (fp32 input)
    k_gemm_mfma<true><<<gemm_grid, 256, 0, stream>>>(x, Wt, dinv, bufA);
    k_spmm<<<NN, 64, 0, stream>>>(bufA, row_start, col, dinv, b1, bufB, 1);
    // layer 2
    k_gemm_mfma<false><<<gemm_grid, 256, 0, stream>>>(bufB, Wt + F * F, dinv, bufA);
    k_spmm<<<NN, 64, 0, stream>>>(bufA, row_start, col, dinv, b2, bufB, 1);
    // layer 3
    k_gemm_mfma<false><<<gemm_grid, 256, 0, stream>>>(bufB, Wt + 2 * F * F, dinv, bufA);
    k_spmm<<<NN, 64, 0, stream>>>(bufA, row_start, col, dinv, b3, bufB, 0);

    k_pool<<<NG * 16, F, 0, stream>>>(bufB, gstart, poolsum);
    k_mlp<<<NG, 64, 0, stream>>>(poolsum, gstart, stats, fw1, fb1, fw2, fb2, fw3, fb3, out);
}